// Round 17
// baseline (250.416 us; speedup 1.0000x reference)
//
#include <hip/hip_runtime.h>
#include <hip/hip_bf16.h>

#define SDIM 1024

typedef float f32x4 __attribute__((ext_vector_type(4)));
typedef float f32x16 __attribute__((ext_vector_type(16)));
typedef short short8 __attribute__((ext_vector_type(8)));

__device__ __forceinline__ unsigned short f2bf(float f) {
    __hip_bfloat16 h = __float2bfloat16(f);
    return *reinterpret_cast<unsigned short*>(&h);
}
__device__ __forceinline__ float bf2f(unsigned short u) {
    return __uint_as_float(((unsigned int)u) << 16);
}
__device__ __forceinline__ void gload_lds16(const unsigned short* g, unsigned short* l) {
    __builtin_amdgcn_global_load_lds((const __attribute__((address_space(1))) void*)g,
                                     (__attribute__((address_space(3))) void*)l, 16, 0, 0);
}

// ------- split-transpose body (uniform branch per block) -------
__device__ __forceinline__ void tr_split(
    const float* __restrict__ in, unsigned short* __restrict__ oh,
    unsigned short* __restrict__ ol, int R, int C, size_t sliceStride,
    int bx, int by, int slice, int tid, float (*t)[33])
{
    int c0 = bx * 32, r0 = by * 32;
    int cc = tid & 31, r8 = tid >> 5;
    const float* ip = in + slice * sliceStride;
    #pragma unroll
    for (int k = 0; k < 4; ++k) {
        int r = r8 + k * 8;
        t[r][cc] = ip[(size_t)(r0 + r) * C + c0 + cc];
    }
    __syncthreads();
    #pragma unroll
    for (int k = 0; k < 4; ++k) {
        int rr = r8 + k * 8;
        float v = t[cc][rr];
        unsigned short hi = f2bf(v);
        unsigned short lo = f2bf(v - bf2f(hi));
        size_t o = slice * sliceStride + (size_t)(c0 + rr) * R + r0 + cc;
        oh[o] = hi; ol[o] = lo;
    }
}

// ---- mega-prep: xT split + w0T split + w1cvt + gate1 (independent block ranges) ----
__global__ __launch_bounds__(256) void prep_kernel(
    const float* __restrict__ inp, const float* __restrict__ w0,
    const float* __restrict__ w1,
    unsigned short* __restrict__ xTh, unsigned short* __restrict__ xTl,
    unsigned short* __restrict__ w0Th, unsigned short* __restrict__ w0Tl,
    unsigned short* __restrict__ w1Th, unsigned short* __restrict__ w1Tl,
    const float* __restrict__ wg, int* __restrict__ idx, float* __restrict__ acc)
{
    __shared__ float t[32][33];
    __shared__ float wgs[4 * 512];
    __shared__ float part[32][4][9];
    __shared__ float la[8];
    int id = blockIdx.x;
    int tid = threadIdx.x;
    if (id < 1024) {                       // xT: [2][512][1024] -> split [2][1024][512]
        int bx = id & 31, by = (id >> 5) & 15, slice = id >> 9;
        tr_split(inp, xTh, xTl, 512, 1024, (size_t)512 * 1024, bx, by, slice, tid, t);
    } else if (id < 7168) {                // w0T: [4][512][3072] -> split [4][3072][512]
        int m = id - 1024;
        int bx = m % 96, by = (m / 96) & 15, slice = m / 1536;
        tr_split(w0, w0Th, w0Tl, 512, 3072, (size_t)512 * 3072, bx, by, slice, tid, t);
    } else if (id < 19456) {               // w1: [3072][1024][3] -> split [3][3072][1024]
        int tt = (id - 7168) * 256 + tid;
        int o = tt >> 10, i = tt & 1023;
        const float* p = w1 + (size_t)o * 3072 + i * 3;
        #pragma unroll
        for (int k = 0; k < 3; ++k) {
            float v = p[k];
            unsigned short hi = f2bf(v);
            unsigned short lo = f2bf(v - bf2f(hi));
            size_t off = (size_t)k * 3145728 + (size_t)o * 1024 + i;
            w1Th[off] = hi; w1Tl[off] = lo;
        }
    } else {                               // gate1: 256 blocks, 8 tokens each
        if (tid < 8) la[tid] = 0.f;
        for (int l = tid; l < 2048; l += 256) wgs[l] = wg[l];
        __syncthreads();
        int t0 = (id - 19456) * 8;
        int b = t0 >> 10, s0 = t0 & 1023;
        int sl = tid & 7, fg = tid >> 3;
        float l0 = 0.f, l1 = 0.f, l2 = 0.f, l3 = 0.f;
        for (int f = fg; f < 512; f += 32) {
            float xv = inp[((size_t)b * 512 + f) * SDIM + s0 + sl];
            l0 += xv * wgs[f];
            l1 += xv * wgs[512 + f];
            l2 += xv * wgs[1024 + f];
            l3 += xv * wgs[1536 + f];
        }
        part[fg][0][sl] = l0; part[fg][1][sl] = l1;
        part[fg][2][sl] = l2; part[fg][3][sl] = l3;
        __syncthreads();
        for (int h = 16; h >= 1; h >>= 1) {
            if (fg < h) {
                #pragma unroll
                for (int e = 0; e < 4; ++e) part[fg][e][sl] += part[fg + h][e][sl];
            }
            __syncthreads();
        }
        if (fg == 0) {
            float L[4] = {part[0][0][sl], part[0][1][sl], part[0][2][sl], part[0][3][sl]};
            float m = fmaxf(fmaxf(L[0], L[1]), fmaxf(L[2], L[3]));
            float e0 = expf(L[0] - m), e1 = expf(L[1] - m), e2 = expf(L[2] - m), e3 = expf(L[3] - m);
            float inv = 1.0f / (e0 + e1 + e2 + e3);
            int best = 0; float bv = L[0];
            if (L[1] > bv) { bv = L[1]; best = 1; }
            if (L[2] > bv) { bv = L[2]; best = 2; }
            if (L[3] > bv) { bv = L[3]; best = 3; }
            idx[t0 + sl] = best;
            atomicAdd(&la[0], e0 * inv);
            atomicAdd(&la[1], e1 * inv);
            atomicAdd(&la[2], e2 * inv);
            atomicAdd(&la[3], e3 * inv);
            atomicAdd(&la[4 + best], 1.0f);
        }
        __syncthreads();
        if (tid < 8) atomicAdd(&acc[tid], la[tid]);
    }
}

// ---------------- token sort: deterministic ballot counting sort per batch ----------
__global__ __launch_bounds__(1024) void sort_kernel(
    const int* __restrict__ idx, int* __restrict__ perm, int* __restrict__ eSorted)
{
    int b = blockIdx.x;
    int tid = threadIdx.x;
    int lane = tid & 63, w = tid >> 6;      // 16 waves
    int e = idx[(b << 10) + tid];
    __shared__ int wcnt[16][4];
    __shared__ int woff[16][4];
    int r = 0;
    unsigned long long lt = (1ull << lane) - 1ull;
    #pragma unroll
    for (int eo = 0; eo < 4; ++eo) {
        unsigned long long m = __ballot(e == eo);
        if (lane == 0) wcnt[w][eo] = __popcll(m);
        if (e == eo) r = __popcll(m & lt);
    }
    __syncthreads();
    if (tid == 0) {
        int baseAcc = 0;
        for (int eo = 0; eo < 4; ++eo)
            for (int ww = 0; ww < 16; ++ww) { woff[ww][eo] = baseAcc; baseAcc += wcnt[ww][eo]; }
    }
    __syncthreads();
    int pos = woff[w][e] + r;
    perm[(b << 10) + pos] = tid;
    eSorted[(b << 10) + pos] = e;
}

// ---- MoE1 split-bf16 MFMA, 96d x 256tok, 768 thr (12 waves of 32d x 64t), dbuf ----
// Per buffer rows(64B): Xh[0,256) Xl[256,512) Wh[512,896) Wl[896,1280); 80 segs
__global__ __launch_bounds__(768) void moe_split_kernel(
    const unsigned short* __restrict__ base, unsigned int XH, unsigned int XL,
    unsigned int WH, unsigned int WL,
    const int* __restrict__ perm, const int* __restrict__ eSorted,
    float* __restrict__ out)
{
    extern __shared__ unsigned short lds[];    // 2 x 40960 ushorts = 160 KiB
    const int BUF = 40960;
    int id = blockIdx.x;
    int wg = (id & 7) * 32 + (id >> 3);        // 256 blocks, XCD-contiguous
    int t0 = (wg & 7) * 256;                   // token fastest -> W L2-resident per XCD
    int d0 = (wg >> 3) * 96;
    int b = t0 >> 10, s0 = t0 & 1023;
    int tid = threadIdx.x;
    int lane = tid & 63;
    int lm = lane & 15, q = lane >> 4;
    int wid = tid >> 6;                        // 0..11
    int wm = (wid >> 2) * 32, wn = (wid & 3) * 64;

    int eLo = eSorted[(b << 10) + s0];
    int eHi = eSorted[(b << 10) + s0 + 255];

    unsigned int gofs[7];
    int lofs[7], doSeg[7];
    #pragma unroll
    for (int j = 0; j < 7; ++j) {
        int seg = wid + 12 * j;                // 0..83; valid < 80
        gofs[j] = 0; lofs[j] = 0; doSeg[j] = 0;
        if (seg < 80) {
            int row = seg * 16 + (lane >> 2);
            int slot = lane & 3;
            int c = slot ^ ((row >> 1) & 3);
            unsigned int src;
            int act = 1;
            if (row < 512) {
                int gr = (row < 256) ? row : row - 256;
                unsigned int hb = (row < 256) ? XH : XL;
                int tj = perm[(b << 10) + s0 + gr];
                src = hb + (unsigned int)(((b << 10) + tj) * 512) + c * 8;
            } else {
                int R = row - 512;
                unsigned int hb = WH;
                if (R >= 384) { R -= 384; hb = WL; }
                int e = R / 96, dl = R - e * 96;
                act = (e >= eLo && e <= eHi) ? 1 : 0;
                src = hb + (unsigned int)((e * 3072 + d0 + dl) * 512) + c * 8;
            }
            gofs[j] = src;
            lofs[j] = seg * 512 + lane * 8;
            doSeg[j] = act;
        }
    }

    int bofH[4];
    #pragma unroll
    for (int fn = 0; fn < 4; ++fn) {
        int row = wn + fn * 16 + lm;           // 0..255
        bofH[fn] = row * 32 + ((q ^ ((row >> 1) & 3)) << 3);
    }
    int aofH[4][2];
    #pragma unroll
    for (int e = 0; e < 4; ++e)
        #pragma unroll
        for (int fm = 0; fm < 2; ++fm) {
            int row = 512 + e * 96 + wm + fm * 16 + lm;
            aofH[e][fm] = row * 32 + ((q ^ ((row >> 1) & 3)) << 3);
        }
    // lo offsets: Xl = +256 rows (+8192), Wl = +384 rows (+12288); swizzle class preserved

    int eidx[4], sv[4];
    #pragma unroll
    for (int fn = 0; fn < 4; ++fn) {
        int sl = (b << 10) + s0 + wn + fn * 16 + lm;
        eidx[fn] = eSorted[sl];
        sv[fn]   = perm[sl];
    }
    bool presF[4][4], presE[4];
    #pragma unroll
    for (int e = 0; e < 4; ++e) {
        presE[e] = false;
        #pragma unroll
        for (int fn = 0; fn < 4; ++fn) {
            presF[e][fn] = __any(eidx[fn] == e);
            presE[e] = presE[e] || presF[e][fn];
        }
    }

    f32x4 acc[2][4];
    #pragma unroll
    for (int fm = 0; fm < 2; ++fm)
        #pragma unroll
        for (int fn = 0; fn < 4; ++fn)
            acc[fm][fn] = (f32x4){0.f, 0.f, 0.f, 0.f};

    const short8 z = {0, 0, 0, 0, 0, 0, 0, 0};

    // prologue: first K-slice DMA into buffer 0
    #pragma unroll
    for (int j = 0; j < 7; ++j)
        if (doSeg[j]) gload_lds16(base + gofs[j], lds + lofs[j]);

    int curOfs = 0;
    for (int f0 = 0; f0 < 512; f0 += 32) {
        __syncthreads();                       // drains DMA for buf[cur]; syncs prev reads
        int nxtOfs = curOfs ^ BUF;
        if (f0 + 32 < 512) {                   // prefetch next K-slice into other buffer
            #pragma unroll
            for (int j = 0; j < 7; ++j)
                if (doSeg[j]) gload_lds16(base + gofs[j] + f0 + 32, lds + nxtOfs + lofs[j]);
        }

        const unsigned short* lb = lds + curOfs;
        short8 bh[4], bl[4];
        #pragma unroll
        for (int fn = 0; fn < 4; ++fn) {
            bh[fn] = *(const short8*)(lb + bofH[fn]);
            bl[fn] = *(const short8*)(lb + bofH[fn] + 8192);
        }
        #pragma unroll
        for (int e = 0; e < 4; ++e) {
            if (presE[e]) {
                short8 ah[2], al[2];
                #pragma unroll
                for (int fm = 0; fm < 2; ++fm) {
                    ah[fm] = *(const short8*)(lb + aofH[e][fm]);
                    al[fm] = *(const short8*)(lb + aofH[e][fm] + 12288);
                }
                __builtin_amdgcn_s_setprio(1);
                #pragma unroll
                for (int fn = 0; fn < 4; ++fn) {
                    if (presF[e][fn]) {
                        short8 bmH = (eidx[fn] == e) ? bh[fn] : z;
                        short8 bmL = (eidx[fn] == e) ? bl[fn] : z;
                        #pragma unroll
                        for (int fm = 0; fm < 2; ++fm) {
                            acc[fm][fn] = __builtin_amdgcn_mfma_f32_16x16x32_bf16(ah[fm], bmH, acc[fm][fn], 0, 0, 0);
                            acc[fm][fn] = __builtin_amdgcn_mfma_f32_16x16x32_bf16(ah[fm], bmL, acc[fm][fn], 0, 0, 0);
                            acc[fm][fn] = __builtin_amdgcn_mfma_f32_16x16x32_bf16(al[fm], bmH, acc[fm][fn], 0, 0, 0);
                        }
                    }
                }
                __builtin_amdgcn_s_setprio(0);
            }
        }
        curOfs = nxtOfs;
    }

    #pragma unroll
    for (int fm = 0; fm < 2; ++fm)
        #pragma unroll
        for (int fn = 0; fn < 4; ++fn) {
            int d = d0 + wm + fm * 16 + q * 4;
            float* op = out + ((size_t)b * 3072 + d) * SDIM + sv[fn];
            #pragma unroll
            for (int r = 0; r < 4; ++r)
                op[(size_t)r * SDIM] = acc[fm][fn][r];
        }
}

// ---- conv1d K=3 split-bf16, 32x32x16 MFMA, 96o x 256tok, 512 thr (8 waves of 96o x 32t)
// Output TRANSPOSED: h1T[b][s][3072].  Per buffer rows(64B): Gh[0,264) Gl[264,528)
// Wh[528,816) Wl[816,1104); 69 segs; dbuf gload_lds prefetch.
__global__ __launch_bounds__(512) void conv_split_kernel(
    const unsigned short* __restrict__ base, unsigned int GH, unsigned int GL,
    unsigned int WH, unsigned int WL, unsigned int ZB, float* __restrict__ h1T)
{
    extern __shared__ unsigned short lds[];    // 2 x 35328 ushorts = 138 KiB
    const int BUF = 35328;
    int id = blockIdx.x;
    int wg = (id & 7) * 32 + (id >> 3);        // 256 blocks, XCD-contiguous
    int t0 = (wg & 7) * 256;                   // token fastest -> W L2-resident per XCD
    int o0 = (wg >> 3) * 96;
    int b = t0 >> 10, s0 = t0 & 1023;
    int tid = threadIdx.x;
    int lane = tid & 63;
    int l32 = lane & 31, half = lane >> 5;     // fragment row/col, k-half
    int wid = tid >> 6;                        // 0..7
    int wn = wid * 32;                         // wave token offset

    unsigned int gofs[9];
    int lofs[9];
    int nseg = (wid < 5) ? 9 : 8;              // 69 segs over 8 waves
    #pragma unroll
    for (int j = 0; j < 9; ++j) {
        int seg = wid + 8 * j;
        gofs[j] = ZB; lofs[j] = 0;
        if (seg < 69) {
            int row = seg * 16 + (lane >> 2);
            int slot = lane & 3;
            int c = slot ^ ((row >> 1) & 3);
            unsigned int src;
            if (row < 528) {
                int gr = (row < 264) ? row : row - 264;
                unsigned int hb = (row < 264) ? GH : GL;
                int s = s0 - 2 + gr;
                if (s < 0) src = ZB + c * 8;                       // causal pad -> zeros
                else { if (s > 1023) s = 1023;                     // tail rows never read
                       src = hb + ((unsigned int)((b << 10) + s) << 10) + c * 8; }
            } else {
                int R = row - 528;
                unsigned int hb = WH;
                if (R >= 288) { R -= 288; hb = WL; }
                int k = R / 96, ol = R - k * 96;
                src = hb + (unsigned int)k * 3145728u + ((unsigned int)(o0 + ol) << 10) + c * 8;
            }
            gofs[j] = src;
            lofs[j] = seg * 512 + lane * 8;
        }
    }

    // 32x32x16 fragment offsets (ushort units); ks = K-half of the 32-i step
    int aofH[3][3][2], aofL[3][3][2], bofH[3][2], bofL[3][2];
    #pragma unroll
    for (int kk = 0; kk < 3; ++kk) {
        #pragma unroll
        for (int fm = 0; fm < 3; ++fm) {
            int R = kk * 96 + fm * 32 + l32;
            int rh = 528 + R, rl = 816 + R;
            #pragma unroll
            for (int ks = 0; ks < 2; ++ks) {
                aofH[kk][fm][ks] = rh * 32 + (((ks * 2 + half) ^ ((rh >> 1) & 3)) << 3);
                aofL[kk][fm][ks] = rl * 32 + (((ks * 2 + half) ^ ((rl >> 1) & 3)) << 3);
            }
        }
        int rbh = wn + l32 + kk;               // token tile row = s - s0 + 2, max 257
        int rbl = rbh + 264;
        #pragma unroll
        for (int ks = 0; ks < 2; ++ks) {
            bofH[kk][ks] = rbh * 32 + (((ks * 2 + half) ^ ((rbh >> 1) & 3)) << 3);
            bofL[kk][ks] = rbl * 32 + (((ks * 2 + half) ^ ((rbl >> 1) & 3)) << 3);
        }
    }

    f32x16 acc[3];
    #pragma unroll
    for (int fm = 0; fm < 3; ++fm)
        #pragma unroll
        for (int j = 0; j < 16; ++j)
            acc[fm][j] = 0.f;

    // prologue: issue first-tile DMA into buffer 0
    #pragma unroll
    for (int j = 0; j < 9; ++j)
        if (j < nseg) gload_lds16(base + gofs[j], lds + lofs[j]);

    int curOfs = 0;
    for (int i0 = 0; i0 < 1024; i0 += 32) {
        __syncthreads();                       // drains DMA for buf[cur]; syncs prev reads
        int nxtOfs = curOfs ^ BUF;
        if (i0 + 32 < 1024) {                  // prefetch next tile into other buffer
            #pragma unroll
            for (int j = 0; j < 9; ++j)
                if (j < nseg) gload_lds16(base + gofs[j] + i0 + 32, lds + nxtOfs + lofs[j]);
        }

        const unsigned short* lb = lds + curOfs;
        #pragma unroll
        for (int ks = 0; ks < 2; ++ks) {
            #pragma unroll
            for (int kk = 0; kk < 3; ++kk) {
                short8 bh = *(const short8*)(lb + bofH[kk][ks]);
                short8 bl = *(const short8*)(lb + bofL[kk][ks]);
                short8 ah[3], al[3];
                #pragma unroll
                for (int fm = 0; fm < 3; ++fm) {
                    ah[fm] = *(const short8*)(lb + aofH[kk][fm][ks]);
                    al[fm] = *(const short8*)(lb + aofL[kk][fm][ks]);
                }
                __builtin_amdgcn_s_setprio(1);
                #pragma unroll
                for (int fm = 0; fm < 3; ++fm) {
                    acc[fm] = __builtin_amdgcn_mfma_f32_32x32x16_bf16(ah[fm], bh, acc[fm], 0, 0, 0);
                    acc[fm] = __builtin_amdgcn_mfma_f32_32x32x16_bf16(ah[fm], bl, acc[fm], 0, 0, 0);
                    acc[fm] = __builtin_amdgcn_mfma_f32_32x32x16_bf16(al[fm], bh, acc[fm], 0, 0, 0);
                }
                __builtin_amdgcn_s_setprio(0);
            }
        }
        curOfs = nxtOfs;
    }

    // transposed epilogue: D col(=token)=lane&31, row(=o)=(reg&3)+8*(reg>>2)+4*half
    int s = s0 + wn + l32;
    float* rowp = h1T + ((size_t)((b << 10) + s)) * 3072 + o0;
    #pragma unroll
    for (int fm = 0; fm < 3; ++fm) {
        #pragma unroll
        for (int r = 0; r < 4; ++r) {
            f32x4 v = {acc[fm][4 * r], acc[fm][4 * r + 1], acc[fm][4 * r + 2], acc[fm][4 * r + 3]};
            *(f32x4*)(rowp + fm * 32 + 8 * r + 4 * half) = v;
        }
    }
}

// ---------------- MoE2 plain-bf16 MFMA + fused loss, 64d x 128 sorted tokens --------
// LDS rows(64B): X[0,128) W[128,384); 24 segs of 16 rows
__global__ __launch_bounds__(256) void moe_kernel(
    const unsigned short* __restrict__ xT, const unsigned short* __restrict__ wT,
    const int* __restrict__ perm, const int* __restrict__ eSorted,
    float* __restrict__ out, int Fdim, int Ddim, const float* __restrict__ accv)
{
    if (blockIdx.x == 0 && threadIdx.x == 0) {     // fused loss (acc final pre-launch)
        float l = 0.f;
        #pragma unroll
        for (int e = 0; e < 4; ++e)
            l += accv[e] * accv[4 + e] + accv[8 + e] * accv[12 + e];
        out[2 * 512 * 1024] = l * (1.0f / (2048.0f * 2048.0f));
    }
    __shared__ unsigned short lds[384 * 32];   // 24 KiB
    int id = blockIdx.x;
    int chunk = gridDim.x >> 3;
    int wg = (id & 7) * chunk + (id >> 3);
    int t0 = (wg & 15) * 128;
    int d0 = (wg >> 4) * 64;
    int b = t0 >> 10, s0 = t0 & 1023;
    int tid = threadIdx.x;
    int lane = tid & 63, wid = tid >> 6;
    int lm = lane & 15, q = lane >> 4;
    int wm = (wid >> 1) * 32, wn = (wid & 1) * 64;

    int eLo = eSorted[(b << 10) + s0];
    int eHi = eSorted[(b << 10) + s0 + 127];

    const unsigned short* gsrc[6];
    int lofs[6], doSeg[6];
    #pragma unroll
    for (int j = 0; j < 6; ++j) {
        int seg = wid + 4 * j;                 // 0..23
        int row = seg * 16 + (lane >> 2);
        int slot = lane & 3;
        int c = slot ^ ((row >> 1) & 3);
        int act = 1;
        const unsigned short* src;
        if (row < 128) {
            int tj = perm[(b << 10) + s0 + row];
            src = xT + (size_t)((b << 10) + tj) * Fdim + c * 8;
        } else {
            int R = row - 128;                 // e*64 + dl
            int e = R >> 6;
            act = (e >= eLo && e <= eHi) ? 1 : 0;
            src = wT + (size_t)(e * Ddim + d0 + (R & 63)) * Fdim + c * 8;
        }
        gsrc[j] = src; lofs[j] = seg * 512 + lane * 8; doSeg[j] = act;
    }

    int bof[4], aof[4][2];
    #pragma unroll
    for (int fn = 0; fn < 4; ++fn) {
        int row = wn + fn * 16 + lm;
        bof[fn] = row * 32 + ((q ^ ((row >> 1) & 3)) << 3);
    }
    #pragma unroll
    for (int e = 0; e < 4; ++e)
        #pragma unroll
        for (int fm = 0; fm < 2; ++fm) {
            int R = 128 + e * 64 + wm + fm * 16 + lm;
            aof[e][fm] = R * 32 + ((q ^ ((R >> 1) & 3)) << 3);
        }

    int eidx[4], sv[4];
    #pragma unroll
    for (int fn = 0; fn < 4; ++fn) {
        int sl = (b << 10) + s0 + wn + fn * 16 + lm;
        eidx[fn] = eSorted[sl];
        sv[fn]   = perm[sl];
    }
    bool presF[4][4], presE[4];
    #pragma unroll
    for (int e = 0; e < 4; ++e) {
        presE[e] = false;
        #pragma unroll
        for (int fn = 0; fn < 4; ++fn) {
            presF[e][fn] = __any(eidx[fn] == e);
            presE[e] = presE[e] || presF[e][fn];
        }
    }

    f32x4 acc[2][4];
    #pragma unroll
    for (int fm = 0; fm < 2; ++fm)
        #pragma unroll
        for (int fn = 0; fn < 4; ++fn)
            acc[fm][fn] = (f32x4){0.f, 0.f, 0.f, 0.f};

    const short8 z = {0, 0, 0, 0, 0, 0, 0, 0};

    for (int f0 = 0; f0 < Fdim; f0 += 32) {
        __syncthreads();
        #pragma unroll
        for (int j = 0; j < 6; ++j)
            if (doSeg[j]) gload_lds16(gsrc[j] + f0, lds + lofs[j]);
        __syncthreads();

        short8 bf[4];
        #pragma unroll
        for (int fn = 0; fn < 4; ++fn)
            bf[fn] = *(const short8*)(lds + bof[fn]);
        #pragma unroll
        for (int e = 0; e < 4; ++e) {
            if (presE[e]) {
                short8 af[2];
                #pragma unroll
                for (int fm = 0; fm < 2; ++fm)
                    af[fm] = *(const short8*)(lds + aof[e][fm]);
                #pragma unroll
                for (int fn = 0; fn < 4; ++fn) {
                    if (presF[e][fn]) {
                        short8 bm = (eidx[fn] == e) ? bf[fn] : z;
                        #pragma unroll
                        for (int fm = 0; fm < 2; ++fm)
                            acc[fm][fn] = __builtin_amdgcn_mfma_f32_16x16x32_bf16(af[fm], bm, acc[fm][fn], 0, 0, 0);
                    }
                }
            }
        }
    }

    #pragma unroll
    for (int fm = 0; fm < 2; ++fm)
        #pragma unroll
        for (int fn = 0; fn < 4; ++fn) {
            int d = d0 + wm + fm * 16 + q * 4;
            float* op = out + ((size_t)b * Ddim + d) * SDIM + sv[fn];
            #pragma unroll
            for (int r = 0; r < 4; ++r)
                op[(size_t)r * SDIM] = acc[fm][fn][r];
        }
}

// ------ cumsum over s + affine (shfl scan) [blocks 0..2047] + w2T transpose [2048..4095]
__global__ __launch_bounds__(256) void cumsum_w2t_kernel(
    const float* __restrict__ h1, const float* __restrict__ divisor,
    float* __restrict__ y, const float* __restrict__ w2, unsigned short* __restrict__ w2T)
{
    __shared__ float tsh[32][33];
    __shared__ float wsum[4];
    int blk = blockIdx.x;
    int tid = threadIdx.x;
    if (blk >= 2048) {                         // w2T: [4][1024][512] -> bf16 [4][512][1024]
        int m = blk - 2048;
        int bx = m & 15, by = (m >> 4) & 31, slice = m >> 9;
        int c0 = bx * 32, r0 = by * 32;
        int cc = tid & 31, r8 = tid >> 5;
        const float* ip = w2 + (size_t)slice * 524288;
        unsigned short* op = w2T + (size_t)slice * 524288;
        #pragma unroll
        for (int k = 0; k < 4; ++k) {
            int r = r8 + k * 8;
            tsh[r][cc] = ip[(size_t)(r0 + r) * 512 + c0 + cc];
        }
        __syncthreads();
        #pragma unroll
        for (int k = 0; k < 4; ++k) {
            int rr = r8 + k * 8;
            op[(size_t)(c0 + rr) * 1024 + r0 + cc] = f2bf(tsh[cc][rr]);
        }
        return;
    }
    int b = blk >> 10, i = blk & 1023;
    const float4* dp = (const float4*)(h1 + ((size_t)b * 3072 + i) * SDIM);
    const float4* sp = (const float4*)(h1 + ((size_t)b * 3072 + 1024 + i) * SDIM);
    const float4* hp = (const float4*)(h1 + ((size_t)b * 3072 + 2048 + i) * SDIM);
    float4 v = dp[tid];
    float c0 = v.x, c1 = c0 + v.y, c2 = c1 + v.z, c3 = c2 + v.w;
    int lane = tid & 63, w = tid >> 6;
    float sc = c3;
    #pragma unroll
    for (int off = 1; off < 64; off <<= 1) {
        float p = __shfl_up(sc, off);
        if (lane >= off) sc += p;
    }
    if (lane == 63) wsum[w] = sc;
    __syncthreads();
    float wbase = 0.f;
    #pragma unroll
    for (int ww = 0; ww < 4; ++ww)
        if (ww < w) wbase += wsum[ww];
    float base = wbase + sc - c3;
    float4 scv = sp[tid], sh = hp[tid];
    float4 dv = ((const float4*)divisor)[tid];
    float4 o;
    o.x = (base + c0) / dv.x * scv.x + sh.x;
    o.y = (base + c1) / dv.y * scv.y + sh.y;
    o.z = (base + c2) / dv.z * scv.z + sh.z;
    o.w = (base + c3) / dv.w * scv.w + sh.w;
    ((float4*)(y + ((size_t)b * 1024 + i) * SDIM))[tid] = o;
}

// ---------------- norm0: channel norm + leaky, split bf16 out [b][s][i] --------------
__global__ __launch_bounds__(256) void norm0_kernel(
    const float* __restrict__ g, unsigned short* __restrict__ oh,
    unsigned short* __restrict__ ol)
{
    int blk = blockIdx.x;
    int b = blk >> 7;
    int s0 = (blk & 127) * 8;
    int tid = threadIdx.x;
    int sg = tid & 7, grp = tid >> 3;
    int s = s0 + sg;
    const float* bp = g + ((size_t)b * 1024) * SDIM + s;
    float v[32];
    float sum = 0.f, ssq = 0.f;
    #pragma unroll
    for (int j = 0; j < 32; ++j) {
        float x = bp[(size_t)(grp * 32 + j) * SDIM];
        v[j] = x; sum += x; ssq += x * x;
    }
    __shared__ float rs[32][8], rq[32][8], stat[2][8];
    rs[grp][sg] = sum; rq[grp][sg] = ssq;
    __syncthreads();
    for (int h = 16; h >= 1; h >>= 1) {
        if (grp < h) { rs[grp][sg] += rs[grp + h][sg]; rq[grp][sg] += rq[grp + h][sg]; }
        __syncthreads();
    }
    if (grp == 0) {
        float S1 = rs[0][sg], S2 = rq[0][sg];
        float mean = S1 * (1.0f / 1024.0f);
        float ssc = fmaxf(S2 - 1024.0f * mean * mean, 0.0f);
        stat[0][sg] = mean;
        stat[1][sg] = 1.0f / (sqrtf(ssc) * (1.0f / 32.0f) + 1e-5f);
    }
    __syncthreads();
    float mean = stat[0][sg], inv = stat[1][sg];
    size_t tbase = (((size_t)b << 10) + s) * 1024 + grp * 32;
    #pragma unroll
    for (int j0 = 0; j0 < 32; j0 += 4) {
        unsigned short uh[4], ul[4];
        #pragma unroll
        for (int jj = 0; jj < 4; ++jj) {
            float o = (v[j0 + jj] - mean) * inv;
            o = (o >= 0.f) ? o : 0.02f * o;
            uh[jj] = f2bf(o);
            ul[jj] = f2bf(o - bf2f(uh[jj]));
        }
        *(ushort4*)(oh + tbase + j0) = (ushort4){uh[0], uh[1], uh[2], uh[3]};
        *(ushort4*)(ol + tbase + j0) = (ushort4){ul[0], ul[1], ul[2], ul[3]};
    }
}

// --- normgate: gated combine + norm + leaky + gate2; reads TRANSPOSED h1T[b][s][3072]
__global__ __launch_bounds__(256) void normgate_kernel(
    const float* __restrict__ h1T, const float* __restrict__ wg,
    unsigned short* __restrict__ outT, int* __restrict__ idx, float* __restrict__ acc)
{
    int blk = blockIdx.x;
    int b = blk >> 7;
    int s0 = (blk & 127) * 8;
    int tid = threadIdx.x;
    int sg = tid & 7, grp = tid >> 3;
    int s = s0 + sg;
    const float* row = h1T + ((size_t)((b << 10) + s)) * 3072;
    float v[32];
    float sum = 0.f, ssq = 0.f;
    #pragma unroll
    for (int j0 = 0; j0 < 32; j0 += 4) {
        int i = grp * 32 + j0;
        float4 av = *(const float4*)(row + i);
        float4 mv = *(const float4*)(row + 1024 + i);
        float4 dv = *(const float4*)(row + 2048 + i);
        float x0 = av.x * mv.x + dv.x;
        float x1 = av.y * mv.y + dv.y;
        float x2 = av.z * mv.z + dv.z;
        float x3 = av.w * mv.w + dv.w;
        v[j0] = x0; v[j0 + 1] = x1; v[j0 + 2] = x2; v[j0 + 3] = x3;
        sum += x0 + x1 + x2 + x3;
        ssq += x0 * x0 + x1 * x1 + x2 * x2 + x3 * x3;
    }
    __shared__ float rs[32][8], rq[32][8], stat[2][8];
    rs[grp][sg] = sum; rq[grp][sg] = ssq;
    __syncthreads();
    for (int h = 16; h >= 1; h >>= 1) {
        if (grp < h) { rs[grp][sg] += rs[grp + h][sg]; rq[grp][sg] += rq[grp + h][sg]; }
        __syncthreads();
    }
    if (grp == 0) {
        float S1 = rs[0][sg], S2 = rq[0][sg];
        float mean = S1 * (1.0f / 1024.0f);
        float ssc = fmaxf(S2 - 1024.0f * mean * mean, 0.0f);
        stat[0][sg] = mean;
        stat[1][sg] = 1.0f / (sqrtf(ssc) * (1.0f / 32.0f) + 1e-5f);
    }
    __syncthreads();
    float mean = stat[0][sg], inv = stat[1][sg];
    float l0 = 0.f, l1 = 0.f, l2 = 0.f, l3 = 0.f;
    size_t tbase = (((size_t)b << 10) + s) * 1024 + grp * 32;
    #pragma unroll
    for (int j0 = 0; j0 < 32; j0 += 4) {
        unsigned short u[4];
        #pragma unroll
        for (int jj = 0; jj < 4; ++jj) {
            int i = grp * 32 + j0 + jj;
            float o = (v[j0 + jj] - mean) * inv;
            o = (o >= 0.f) ? o : 0.02f * o;
            u[jj] = f2bf(o);
            l0 += o * wg[i];
            l1 += o * wg[1024 + i];
            l2 += o * wg[2048 + i];
            l3 += o * wg[3072 + i];
        }
        *(ushort4*)(outT + tbase + j0) = (ushort4){u[0], u[1], u[2], u[3]};
    }
    __shared__ float pl[4][32][8];
    __shared__ float la[8];
    pl[0][grp][sg] = l0; pl[1][grp][sg] = l1;
    pl[2][grp][sg] = l2; pl[3][grp][sg] = l3;
    if (tid < 8) la[tid] = 0.f;
    __syncthreads();
    for (int h = 16; h >= 1; h >>= 1) {
        if (grp < h) {
            #pragma unroll
            for (int e = 0; e < 4; ++e) pl[e][grp][sg] += pl[e][grp + h][sg];
        }
        __syncthreads();
    }
    if (grp == 0) {
        float L[4] = {pl[0][0][sg], pl[1][0][sg], pl[2][0][sg], pl[3][0][sg]};
        float m = fmaxf(fmaxf(L[0], L[1]), fmaxf(L[2], L[3]));
        float e0 = expf(L[0] - m), e1 = expf(L[1] - m), e2 = expf(L[2] - m), e3 = expf(L[3] - m);
        float invs = 1.0f / (e0 + e1 + e2 + e3);
        int best = 0; float bv = L[0];
        if (L[1] > bv) { bv = L[1]; best = 1; }
        if (L[2] > bv) { bv = L[2]; best = 2; }
        if (L[3] > bv) { bv = L[3]; best = 3; }
        idx[(b << 10) + s] = best;
        atomicAdd(&la[0], e0 * invs);
        atomicAdd(&la[1], e1 * invs);
        atomicAdd(&la[2], e2 * invs);
        atomicAdd(&la[3], e3 * invs);
        atomicAdd(&la[4 + best], 1.0f);
    }
    __syncthreads();
    if (tid < 8) atomicAdd(&acc[8 + tid], la[tid]);
}

extern "C" void kernel_launch(void* const* d_in, const int* in_sizes, int n_in,
                              void* d_out, int out_size, void* d_ws, size_t ws_size,
                              hipStream_t stream) {
    const float* inp     = (const float*)d_in[0];
    const float* divisor = (const float*)d_in[1];
    const float* w0_gate = (const float*)d_in[2];
    const float* w0      = (const float*)d_in[3];
    const float* w1      = (const float*)d_in[4];
    const float* w2_gate = (const float*)d_in[5];
    const float* w2      = (const float*)d_in[6];
    float* out = (float*)d_out;
    (void)in_sizes; (void)n_in; (void)out_size; (void)ws_size;

    char* ws = (char*)d_ws;
    const unsigned short* base = (const unsigned short*)ws;

    float* h1            = (float*)(ws + 0);                  // 25165824 (also h1T)
    float* g             = (float*)(ws + 25165824);           //  8388608
    unsigned short* gT1h = (unsigned short*)(ws + 33554432);  //  4194304
    unsigned short* gT1l = (unsigned short*)(ws + 37748736);  //  4194304
    unsigned short* w1Th = (unsigned short*)(ws + 41943040);  // 18874368
    unsigned short* w1Tl = (unsigned short*)(ws + 60817408);  // 18874368
    unsigned short* xTh  = (unsigned short*)(ws + 79691776);  //  2097152
    unsigned short* xTl  = (unsigned short*)(ws + 81788928);  //  2097152
    unsigned short* w0Th = (unsigned short*)(ws + 83886080);  // 12582912
    unsigned short* w0Tl = (unsigned short*)(ws + 96468992);  // 12582912
    unsigned short* gT2  = (unsigned short*)(ws + 79691776);  //  4194304 (reuse)
    unsigned short* w2T  = (unsigned short*)(ws + 83886080);  //  4194304 (reuse)
    int* idx1            = (int*)(ws + 109051904);
    int* idx2            = (int*)(ws + 109060096);
    float* acc           = (float*)(ws + 109068288);
    int* perm1           = (int*)(ws + 109076480);
    int* eSort1          = (int*)(ws + 109084672);
    int* perm2           = (int*)(ws + 109092864);
    int* eSort2          = (int*)(ws + 109101056);
    float* zbuf          = (float*)(ws + 109109248);          // 4096 B zeros

    const unsigned int GT1H = 16777216u, GT1L = 18874368u;
    const unsigned int W1TH = 20971520u, W1TL = 30408704u;
    const unsigned int XTH  = 39845888u, XTL  = 40894464u;
    const unsigned int W0TH = 41943040u, W0TL = 48234496u;
    const unsigned int ZB   = 54554624u;                      // zbuf in ushort units

    hipMemsetAsync(acc, 0, 64, stream);
    hipMemsetAsync(zbuf, 0, 4096, stream);

    // fused prep: xT/w0T split transposes + w1 split cvt + gate1
    prep_kernel<<<19712, 256, 0, stream>>>(inp, w0, w1, xTh, xTl, w0Th, w0Tl,
                                           w1Th, w1Tl, w0_gate, idx1, acc);

    sort_kernel<<<2, 1024, 0, stream>>>(idx1, perm1, eSort1);
    // MoE 1 (split), 768-thread 12-wave dbuf
    moe_split_kernel<<<256, 768, 163840, stream>>>(base, XTH, XTL, W0TH, W0TL, perm1, eSort1, h1);

    // cumsum + affine (shfl scan) fused with w2T transpose
    cumsum_w2t_kernel<<<4096, 256, 0, stream>>>(h1, divisor, g, w2, w2T);
    norm0_kernel<<<256, 256, 0, stream>>>(g, gT1h, gT1l);
    // conv (split), 512-thread 8-wave dbuf, 32x32x16 MFMA, transposed output h1T
    conv_split_kernel<<<256, 512, 141312, stream>>>(base, GT1H, GT1L, W1TH, W1TL, ZB, h1);
    // fused gated-combine + norm + leaky + gate2 (reads h1T)
    normgate_kernel<<<256, 256, 0, stream>>>(h1, w2_gate, gT2, idx2, acc);

    // MoE 2 (plain bf16) + fused loss
    sort_kernel<<<2, 1024, 0, stream>>>(idx2, perm2, eSort2);
    moe_kernel<<<128, 256, 0, stream>>>(gT2, w2T, perm2, eSort2, out, 1024, 512, acc);
}

// Round 18
// 233.125 us; speedup vs baseline: 1.0742x; 1.0742x over previous
//
#include <hip/hip_runtime.h>
#include <hip/hip_bf16.h>

#define SDIM 1024

typedef float f32x4 __attribute__((ext_vector_type(4)));
typedef short short8 __attribute__((ext_vector_type(8)));

__device__ __forceinline__ unsigned short f2bf(float f) {
    __hip_bfloat16 h = __float2bfloat16(f);
    return *reinterpret_cast<unsigned short*>(&h);
}
__device__ __forceinline__ float bf2f(unsigned short u) {
    return __uint_as_float(((unsigned int)u) << 16);
}
__device__ __forceinline__ void gload_lds16(const unsigned short* g, unsigned short* l) {
    __builtin_amdgcn_global_load_lds((const __attribute__((address_space(1))) void*)g,
                                     (__attribute__((address_space(3))) void*)l, 16, 0, 0);
}

// ------- split-transpose body (uniform branch per block) -------
__device__ __forceinline__ void tr_split(
    const float* __restrict__ in, unsigned short* __restrict__ oh,
    unsigned short* __restrict__ ol, int R, int C, size_t sliceStride,
    int bx, int by, int slice, int tid, float (*t)[33])
{
    int c0 = bx * 32, r0 = by * 32;
    int cc = tid & 31, r8 = tid >> 5;
    const float* ip = in + slice * sliceStride;
    #pragma unroll
    for (int k = 0; k < 4; ++k) {
        int r = r8 + k * 8;
        t[r][cc] = ip[(size_t)(r0 + r) * C + c0 + cc];
    }
    __syncthreads();
    #pragma unroll
    for (int k = 0; k < 4; ++k) {
        int rr = r8 + k * 8;
        float v = t[cc][rr];
        unsigned short hi = f2bf(v);
        unsigned short lo = f2bf(v - bf2f(hi));
        size_t o = slice * sliceStride + (size_t)(c0 + rr) * R + r0 + cc;
        oh[o] = hi; ol[o] = lo;
    }
}

// ---- mega-prep: xT split + w0T split + w1cvt + gate1 (independent block ranges) ----
__global__ __launch_bounds__(256) void prep_kernel(
    const float* __restrict__ inp, const float* __restrict__ w0,
    const float* __restrict__ w1,
    unsigned short* __restrict__ xTh, unsigned short* __restrict__ xTl,
    unsigned short* __restrict__ w0Th, unsigned short* __restrict__ w0Tl,
    unsigned short* __restrict__ w1Th, unsigned short* __restrict__ w1Tl,
    const float* __restrict__ wg, int* __restrict__ idx, float* __restrict__ acc)
{
    __shared__ float t[32][33];
    __shared__ float wgs[4 * 512];
    __shared__ float part[32][4][9];
    __shared__ float la[8];
    int id = blockIdx.x;
    int tid = threadIdx.x;
    if (id < 1024) {                       // xT: [2][512][1024] -> split [2][1024][512]
        int bx = id & 31, by = (id >> 5) & 15, slice = id >> 9;
        tr_split(inp, xTh, xTl, 512, 1024, (size_t)512 * 1024, bx, by, slice, tid, t);
    } else if (id < 7168) {                // w0T: [4][512][3072] -> split [4][3072][512]
        int m = id - 1024;
        int bx = m % 96, by = (m / 96) & 15, slice = m / 1536;
        tr_split(w0, w0Th, w0Tl, 512, 3072, (size_t)512 * 3072, bx, by, slice, tid, t);
    } else if (id < 19456) {               // w1: [3072][1024][3] -> split [3][3072][1024]
        int tt = (id - 7168) * 256 + tid;
        int o = tt >> 10, i = tt & 1023;
        const float* p = w1 + (size_t)o * 3072 + i * 3;
        #pragma unroll
        for (int k = 0; k < 3; ++k) {
            float v = p[k];
            unsigned short hi = f2bf(v);
            unsigned short lo = f2bf(v - bf2f(hi));
            size_t off = (size_t)k * 3145728 + (size_t)o * 1024 + i;
            w1Th[off] = hi; w1Tl[off] = lo;
        }
    } else {                               // gate1: 256 blocks, 8 tokens each
        if (tid < 8) la[tid] = 0.f;
        for (int l = tid; l < 2048; l += 256) wgs[l] = wg[l];
        __syncthreads();
        int t0 = (id - 19456) * 8;
        int b = t0 >> 10, s0 = t0 & 1023;
        int sl = tid & 7, fg = tid >> 3;
        float l0 = 0.f, l1 = 0.f, l2 = 0.f, l3 = 0.f;
        for (int f = fg; f < 512; f += 32) {
            float xv = inp[((size_t)b * 512 + f) * SDIM + s0 + sl];
            l0 += xv * wgs[f];
            l1 += xv * wgs[512 + f];
            l2 += xv * wgs[1024 + f];
            l3 += xv * wgs[1536 + f];
        }
        part[fg][0][sl] = l0; part[fg][1][sl] = l1;
        part[fg][2][sl] = l2; part[fg][3][sl] = l3;
        __syncthreads();
        for (int h = 16; h >= 1; h >>= 1) {
            if (fg < h) {
                #pragma unroll
                for (int e = 0; e < 4; ++e) part[fg][e][sl] += part[fg + h][e][sl];
            }
            __syncthreads();
        }
        if (fg == 0) {
            float L[4] = {part[0][0][sl], part[0][1][sl], part[0][2][sl], part[0][3][sl]};
            float m = fmaxf(fmaxf(L[0], L[1]), fmaxf(L[2], L[3]));
            float e0 = expf(L[0] - m), e1 = expf(L[1] - m), e2 = expf(L[2] - m), e3 = expf(L[3] - m);
            float inv = 1.0f / (e0 + e1 + e2 + e3);
            int best = 0; float bv = L[0];
            if (L[1] > bv) { bv = L[1]; best = 1; }
            if (L[2] > bv) { bv = L[2]; best = 2; }
            if (L[3] > bv) { bv = L[3]; best = 3; }
            idx[t0 + sl] = best;
            atomicAdd(&la[0], e0 * inv);
            atomicAdd(&la[1], e1 * inv);
            atomicAdd(&la[2], e2 * inv);
            atomicAdd(&la[3], e3 * inv);
            atomicAdd(&la[4 + best], 1.0f);
        }
        __syncthreads();
        if (tid < 8) atomicAdd(&acc[tid], la[tid]);
    }
}

// ---------------- token sort: deterministic ballot counting sort per batch ----------
__global__ __launch_bounds__(1024) void sort_kernel(
    const int* __restrict__ idx, int* __restrict__ perm, int* __restrict__ eSorted)
{
    int b = blockIdx.x;
    int tid = threadIdx.x;
    int lane = tid & 63, w = tid >> 6;      // 16 waves
    int e = idx[(b << 10) + tid];
    __shared__ int wcnt[16][4];
    __shared__ int woff[16][4];
    int r = 0;
    unsigned long long lt = (1ull << lane) - 1ull;
    #pragma unroll
    for (int eo = 0; eo < 4; ++eo) {
        unsigned long long m = __ballot(e == eo);
        if (lane == 0) wcnt[w][eo] = __popcll(m);
        if (e == eo) r = __popcll(m & lt);
    }
    __syncthreads();
    if (tid == 0) {
        int baseAcc = 0;
        for (int eo = 0; eo < 4; ++eo)
            for (int ww = 0; ww < 16; ++ww) { woff[ww][eo] = baseAcc; baseAcc += wcnt[ww][eo]; }
    }
    __syncthreads();
    int pos = woff[w][e] + r;
    perm[(b << 10) + pos] = tid;
    eSorted[(b << 10) + pos] = e;
}

// ---- MoE1 split-bf16 MFMA, 96d x 256tok, 768 thr (12 waves of 32d x 64t), dbuf ----
// Per buffer rows(64B): Xh[0,256) Xl[256,512) Wh[512,896) Wl[896,1280); 80 segs
__global__ __launch_bounds__(768) void moe_split_kernel(
    const unsigned short* __restrict__ base, unsigned int XH, unsigned int XL,
    unsigned int WH, unsigned int WL,
    const int* __restrict__ perm, const int* __restrict__ eSorted,
    float* __restrict__ out)
{
    extern __shared__ unsigned short lds[];    // 2 x 40960 ushorts = 160 KiB
    const int BUF = 40960;
    int id = blockIdx.x;
    int wg = (id & 7) * 32 + (id >> 3);        // 256 blocks, XCD-contiguous
    int t0 = (wg & 7) * 256;                   // token fastest -> W L2-resident per XCD
    int d0 = (wg >> 3) * 96;
    int b = t0 >> 10, s0 = t0 & 1023;
    int tid = threadIdx.x;
    int lane = tid & 63;
    int lm = lane & 15, q = lane >> 4;
    int wid = tid >> 6;                        // 0..11
    int wm = (wid >> 2) * 32, wn = (wid & 3) * 64;

    int eLo = eSorted[(b << 10) + s0];
    int eHi = eSorted[(b << 10) + s0 + 255];

    unsigned int gofs[7];
    int lofs[7], doSeg[7];
    #pragma unroll
    for (int j = 0; j < 7; ++j) {
        int seg = wid + 12 * j;                // 0..83; valid < 80
        gofs[j] = 0; lofs[j] = 0; doSeg[j] = 0;
        if (seg < 80) {
            int row = seg * 16 + (lane >> 2);
            int slot = lane & 3;
            int c = slot ^ ((row >> 1) & 3);
            unsigned int src;
            int act = 1;
            if (row < 512) {
                int gr = (row < 256) ? row : row - 256;
                unsigned int hb = (row < 256) ? XH : XL;
                int tj = perm[(b << 10) + s0 + gr];
                src = hb + (unsigned int)(((b << 10) + tj) * 512) + c * 8;
            } else {
                int R = row - 512;
                unsigned int hb = WH;
                if (R >= 384) { R -= 384; hb = WL; }
                int e = R / 96, dl = R - e * 96;
                act = (e >= eLo && e <= eHi) ? 1 : 0;
                src = hb + (unsigned int)((e * 3072 + d0 + dl) * 512) + c * 8;
            }
            gofs[j] = src;
            lofs[j] = seg * 512 + lane * 8;
            doSeg[j] = act;
        }
    }

    int bofH[4];
    #pragma unroll
    for (int fn = 0; fn < 4; ++fn) {
        int row = wn + fn * 16 + lm;           // 0..255
        bofH[fn] = row * 32 + ((q ^ ((row >> 1) & 3)) << 3);
    }
    int aofH[4][2];
    #pragma unroll
    for (int e = 0; e < 4; ++e)
        #pragma unroll
        for (int fm = 0; fm < 2; ++fm) {
            int row = 512 + e * 96 + wm + fm * 16 + lm;
            aofH[e][fm] = row * 32 + ((q ^ ((row >> 1) & 3)) << 3);
        }
    // lo offsets: Xl = +256 rows (+8192), Wl = +384 rows (+12288); swizzle class preserved

    int eidx[4], sv[4];
    #pragma unroll
    for (int fn = 0; fn < 4; ++fn) {
        int sl = (b << 10) + s0 + wn + fn * 16 + lm;
        eidx[fn] = eSorted[sl];
        sv[fn]   = perm[sl];
    }
    bool presF[4][4], presE[4];
    #pragma unroll
    for (int e = 0; e < 4; ++e) {
        presE[e] = false;
        #pragma unroll
        for (int fn = 0; fn < 4; ++fn) {
            presF[e][fn] = __any(eidx[fn] == e);
            presE[e] = presE[e] || presF[e][fn];
        }
    }

    f32x4 acc[2][4];
    #pragma unroll
    for (int fm = 0; fm < 2; ++fm)
        #pragma unroll
        for (int fn = 0; fn < 4; ++fn)
            acc[fm][fn] = (f32x4){0.f, 0.f, 0.f, 0.f};

    const short8 z = {0, 0, 0, 0, 0, 0, 0, 0};

    // prologue: first K-slice DMA into buffer 0
    #pragma unroll
    for (int j = 0; j < 7; ++j)
        if (doSeg[j]) gload_lds16(base + gofs[j], lds + lofs[j]);

    int curOfs = 0;
    for (int f0 = 0; f0 < 512; f0 += 32) {
        __syncthreads();                       // drains DMA for buf[cur]; syncs prev reads
        int nxtOfs = curOfs ^ BUF;
        if (f0 + 32 < 512) {                   // prefetch next K-slice into other buffer
            #pragma unroll
            for (int j = 0; j < 7; ++j)
                if (doSeg[j]) gload_lds16(base + gofs[j] + f0 + 32, lds + nxtOfs + lofs[j]);
        }

        const unsigned short* lb = lds + curOfs;
        short8 bh[4], bl[4];
        #pragma unroll
        for (int fn = 0; fn < 4; ++fn) {
            bh[fn] = *(const short8*)(lb + bofH[fn]);
            bl[fn] = *(const short8*)(lb + bofH[fn] + 8192);
        }
        #pragma unroll
        for (int e = 0; e < 4; ++e) {
            if (presE[e]) {
                short8 ah[2], al[2];
                #pragma unroll
                for (int fm = 0; fm < 2; ++fm) {
                    ah[fm] = *(const short8*)(lb + aofH[e][fm]);
                    al[fm] = *(const short8*)(lb + aofH[e][fm] + 12288);
                }
                __builtin_amdgcn_s_setprio(1);
                #pragma unroll
                for (int fn = 0; fn < 4; ++fn) {
                    if (presF[e][fn]) {
                        short8 bmH = (eidx[fn] == e) ? bh[fn] : z;
                        short8 bmL = (eidx[fn] == e) ? bl[fn] : z;
                        #pragma unroll
                        for (int fm = 0; fm < 2; ++fm) {
                            acc[fm][fn] = __builtin_amdgcn_mfma_f32_16x16x32_bf16(ah[fm], bmH, acc[fm][fn], 0, 0, 0);
                            acc[fm][fn] = __builtin_amdgcn_mfma_f32_16x16x32_bf16(ah[fm], bmL, acc[fm][fn], 0, 0, 0);
                            acc[fm][fn] = __builtin_amdgcn_mfma_f32_16x16x32_bf16(al[fm], bmH, acc[fm][fn], 0, 0, 0);
                        }
                    }
                }
                __builtin_amdgcn_s_setprio(0);
            }
        }
        curOfs = nxtOfs;
    }

    #pragma unroll
    for (int fm = 0; fm < 2; ++fm)
        #pragma unroll
        for (int fn = 0; fn < 4; ++fn) {
            int d = d0 + wm + fm * 16 + q * 4;
            float* op = out + ((size_t)b * 3072 + d) * SDIM + sv[fn];
            #pragma unroll
            for (int r = 0; r < 4; ++r)
                op[(size_t)r * SDIM] = acc[fm][fn][r];
        }
}

// ---- conv1d K=3 split-bf16, 16x16x32 MFMA, 96o x 256tok, 512 thr -------------------
// 8 waves of 96o x 32t (fm=6, fn=2): LDS reads 480 -> 384 per CU-K-step.
// Output TRANSPOSED: h1T[b][s][3072].  Per buffer rows(64B): Gh[0,264) Gl[264,528)
// Wh[528,816) Wl[816,1104); 69 segs; dbuf gload_lds prefetch.
__global__ __launch_bounds__(512) void conv_split_kernel(
    const unsigned short* __restrict__ base, unsigned int GH, unsigned int GL,
    unsigned int WH, unsigned int WL, unsigned int ZB, float* __restrict__ h1T)
{
    extern __shared__ unsigned short lds[];    // 2 x 35328 ushorts = 138 KiB
    const int BUF = 35328;
    int id = blockIdx.x;
    int wg = (id & 7) * 32 + (id >> 3);        // 256 blocks, XCD-contiguous
    int t0 = (wg & 7) * 256;                   // token fastest -> W L2-resident per XCD
    int o0 = (wg >> 3) * 96;
    int b = t0 >> 10, s0 = t0 & 1023;
    int tid = threadIdx.x;
    int lane = tid & 63;
    int lm = lane & 15, q = lane >> 4;
    int wid = tid >> 6;                        // 0..7
    int wn = wid * 32;                         // wave token offset; fn in 0..1

    unsigned int gofs[9];
    int lofs[9];
    int nseg = (wid < 5) ? 9 : 8;              // 69 segs over 8 waves
    #pragma unroll
    for (int j = 0; j < 9; ++j) {
        int seg = wid + 8 * j;
        gofs[j] = ZB; lofs[j] = 0;
        if (seg < 69) {
            int row = seg * 16 + (lane >> 2);
            int slot = lane & 3;
            int c = slot ^ ((row >> 1) & 3);
            unsigned int src;
            if (row < 528) {
                int gr = (row < 264) ? row : row - 264;
                unsigned int hb = (row < 264) ? GH : GL;
                int s = s0 - 2 + gr;
                if (s < 0) src = ZB + c * 8;                       // causal pad -> zeros
                else { if (s > 1023) s = 1023;                     // tail rows never read
                       src = hb + ((unsigned int)((b << 10) + s) << 10) + c * 8; }
            } else {
                int R = row - 528;
                unsigned int hb = WH;
                if (R >= 288) { R -= 288; hb = WL; }
                int k = R / 96, ol = R - k * 96;
                src = hb + (unsigned int)k * 3145728u + ((unsigned int)(o0 + ol) << 10) + c * 8;
            }
            gofs[j] = src;
            lofs[j] = seg * 512 + lane * 8;
        }
    }

    int aofH[3][6], aofL[3][6], bofH[3][2], bofL[3][2];
    #pragma unroll
    for (int kk = 0; kk < 3; ++kk) {
        #pragma unroll
        for (int fm = 0; fm < 6; ++fm) {
            int R = kk * 96 + fm * 16 + lm;
            int rh = 528 + R, rl = 816 + R;
            aofH[kk][fm] = rh * 32 + ((q ^ ((rh >> 1) & 3)) << 3);
            aofL[kk][fm] = rl * 32 + ((q ^ ((rl >> 1) & 3)) << 3);
        }
        #pragma unroll
        for (int fn = 0; fn < 2; ++fn) {
            int rh = wn + fn * 16 + lm + kk;    // tile row = s - s0 + 2, max 257
            int rl = rh + 264;
            bofH[kk][fn] = rh * 32 + ((q ^ ((rh >> 1) & 3)) << 3);
            bofL[kk][fn] = rl * 32 + ((q ^ ((rl >> 1) & 3)) << 3);
        }
    }

    f32x4 acc[6][2];
    #pragma unroll
    for (int fm = 0; fm < 6; ++fm)
        #pragma unroll
        for (int fn = 0; fn < 2; ++fn)
            acc[fm][fn] = (f32x4){0.f, 0.f, 0.f, 0.f};

    // prologue: issue first-tile DMA into buffer 0
    #pragma unroll
    for (int j = 0; j < 9; ++j)
        if (j < nseg) gload_lds16(base + gofs[j], lds + lofs[j]);

    int curOfs = 0;
    for (int i0 = 0; i0 < 1024; i0 += 32) {
        __syncthreads();                       // drains DMA for buf[cur]; syncs prev reads
        int nxtOfs = curOfs ^ BUF;
        if (i0 + 32 < 1024) {                  // prefetch next tile into other buffer
            #pragma unroll
            for (int j = 0; j < 9; ++j)
                if (j < nseg) gload_lds16(base + gofs[j] + i0 + 32, lds + nxtOfs + lofs[j]);
        }

        const unsigned short* lb = lds + curOfs;
        #pragma unroll
        for (int kk = 0; kk < 3; ++kk) {
            short8 ah[6], al[6], bh[2], bl[2];
            #pragma unroll
            for (int fm = 0; fm < 6; ++fm) {
                ah[fm] = *(const short8*)(lb + aofH[kk][fm]);
                al[fm] = *(const short8*)(lb + aofL[kk][fm]);
            }
            #pragma unroll
            for (int fn = 0; fn < 2; ++fn) {
                bh[fn] = *(const short8*)(lb + bofH[kk][fn]);
                bl[fn] = *(const short8*)(lb + bofL[kk][fn]);
            }
            __builtin_amdgcn_s_setprio(1);
            #pragma unroll
            for (int fm = 0; fm < 6; ++fm)
                #pragma unroll
                for (int fn = 0; fn < 2; ++fn) {
                    acc[fm][fn] = __builtin_amdgcn_mfma_f32_16x16x32_bf16(ah[fm], bh[fn], acc[fm][fn], 0, 0, 0);
                    acc[fm][fn] = __builtin_amdgcn_mfma_f32_16x16x32_bf16(ah[fm], bl[fn], acc[fm][fn], 0, 0, 0);
                    acc[fm][fn] = __builtin_amdgcn_mfma_f32_16x16x32_bf16(al[fm], bh[fn], acc[fm][fn], 0, 0, 0);
                }
            __builtin_amdgcn_s_setprio(0);
        }
        curOfs = nxtOfs;
    }

    // transposed epilogue: one f32x4 store per fragment (o contiguous)
    #pragma unroll
    for (int fm = 0; fm < 6; ++fm)
        #pragma unroll
        for (int fn = 0; fn < 2; ++fn) {
            int o = o0 + fm * 16 + q * 4;
            int s = s0 + wn + fn * 16 + lm;
            *(f32x4*)(h1T + ((size_t)((b << 10) + s)) * 3072 + o) = acc[fm][fn];
        }
}

// ---------------- MoE2 plain-bf16 MFMA + fused loss, 64d x 128 sorted tokens --------
// LDS rows(64B): X[0,128) W[128,384); 24 segs of 16 rows
__global__ __launch_bounds__(256) void moe_kernel(
    const unsigned short* __restrict__ xT, const unsigned short* __restrict__ wT,
    const int* __restrict__ perm, const int* __restrict__ eSorted,
    float* __restrict__ out, int Fdim, int Ddim, const float* __restrict__ accv)
{
    if (blockIdx.x == 0 && threadIdx.x == 0) {     // fused loss (acc final pre-launch)
        float l = 0.f;
        #pragma unroll
        for (int e = 0; e < 4; ++e)
            l += accv[e] * accv[4 + e] + accv[8 + e] * accv[12 + e];
        out[2 * 512 * 1024] = l * (1.0f / (2048.0f * 2048.0f));
    }
    __shared__ unsigned short lds[384 * 32];   // 24 KiB
    int id = blockIdx.x;
    int chunk = gridDim.x >> 3;
    int wg = (id & 7) * chunk + (id >> 3);
    int t0 = (wg & 15) * 128;
    int d0 = (wg >> 4) * 64;
    int b = t0 >> 10, s0 = t0 & 1023;
    int tid = threadIdx.x;
    int lane = tid & 63, wid = tid >> 6;
    int lm = lane & 15, q = lane >> 4;
    int wm = (wid >> 1) * 32, wn = (wid & 1) * 64;

    int eLo = eSorted[(b << 10) + s0];
    int eHi = eSorted[(b << 10) + s0 + 127];

    const unsigned short* gsrc[6];
    int lofs[6], doSeg[6];
    #pragma unroll
    for (int j = 0; j < 6; ++j) {
        int seg = wid + 4 * j;                 // 0..23
        int row = seg * 16 + (lane >> 2);
        int slot = lane & 3;
        int c = slot ^ ((row >> 1) & 3);
        int act = 1;
        const unsigned short* src;
        if (row < 128) {
            int tj = perm[(b << 10) + s0 + row];
            src = xT + (size_t)((b << 10) + tj) * Fdim + c * 8;
        } else {
            int R = row - 128;                 // e*64 + dl
            int e = R >> 6;
            act = (e >= eLo && e <= eHi) ? 1 : 0;
            src = wT + (size_t)(e * Ddim + d0 + (R & 63)) * Fdim + c * 8;
        }
        gsrc[j] = src; lofs[j] = seg * 512 + lane * 8; doSeg[j] = act;
    }

    int bof[4], aof[4][2];
    #pragma unroll
    for (int fn = 0; fn < 4; ++fn) {
        int row = wn + fn * 16 + lm;
        bof[fn] = row * 32 + ((q ^ ((row >> 1) & 3)) << 3);
    }
    #pragma unroll
    for (int e = 0; e < 4; ++e)
        #pragma unroll
        for (int fm = 0; fm < 2; ++fm) {
            int R = 128 + e * 64 + wm + fm * 16 + lm;
            aof[e][fm] = R * 32 + ((q ^ ((R >> 1) & 3)) << 3);
        }

    int eidx[4], sv[4];
    #pragma unroll
    for (int fn = 0; fn < 4; ++fn) {
        int sl = (b << 10) + s0 + wn + fn * 16 + lm;
        eidx[fn] = eSorted[sl];
        sv[fn]   = perm[sl];
    }
    bool presF[4][4], presE[4];
    #pragma unroll
    for (int e = 0; e < 4; ++e) {
        presE[e] = false;
        #pragma unroll
        for (int fn = 0; fn < 4; ++fn) {
            presF[e][fn] = __any(eidx[fn] == e);
            presE[e] = presE[e] || presF[e][fn];
        }
    }

    f32x4 acc[2][4];
    #pragma unroll
    for (int fm = 0; fm < 2; ++fm)
        #pragma unroll
        for (int fn = 0; fn < 4; ++fn)
            acc[fm][fn] = (f32x4){0.f, 0.f, 0.f, 0.f};

    const short8 z = {0, 0, 0, 0, 0, 0, 0, 0};

    for (int f0 = 0; f0 < Fdim; f0 += 32) {
        __syncthreads();
        #pragma unroll
        for (int j = 0; j < 6; ++j)
            if (doSeg[j]) gload_lds16(gsrc[j] + f0, lds + lofs[j]);
        __syncthreads();

        short8 bf[4];
        #pragma unroll
        for (int fn = 0; fn < 4; ++fn)
            bf[fn] = *(const short8*)(lds + bof[fn]);
        #pragma unroll
        for (int e = 0; e < 4; ++e) {
            if (presE[e]) {
                short8 af[2];
                #pragma unroll
                for (int fm = 0; fm < 2; ++fm)
                    af[fm] = *(const short8*)(lds + aof[e][fm]);
                #pragma unroll
                for (int fn = 0; fn < 4; ++fn) {
                    if (presF[e][fn]) {
                        short8 bm = (eidx[fn] == e) ? bf[fn] : z;
                        #pragma unroll
                        for (int fm = 0; fm < 2; ++fm)
                            acc[fm][fn] = __builtin_amdgcn_mfma_f32_16x16x32_bf16(af[fm], bm, acc[fm][fn], 0, 0, 0);
                    }
                }
            }
        }
    }

    #pragma unroll
    for (int fm = 0; fm < 2; ++fm)
        #pragma unroll
        for (int fn = 0; fn < 4; ++fn) {
            int d = d0 + wm + fm * 16 + q * 4;
            float* op = out + ((size_t)b * Ddim + d) * SDIM + sv[fn];
            #pragma unroll
            for (int r = 0; r < 4; ++r)
                op[(size_t)r * SDIM] = acc[fm][fn][r];
        }
}

// ------ cumsum over s + affine (shfl scan) [blocks 0..2047] + w2T transpose [2048..4095]
__global__ __launch_bounds__(256) void cumsum_w2t_kernel(
    const float* __restrict__ h1, const float* __restrict__ divisor,
    float* __restrict__ y, const float* __restrict__ w2, unsigned short* __restrict__ w2T)
{
    __shared__ float tsh[32][33];
    __shared__ float wsum[4];
    int blk = blockIdx.x;
    int tid = threadIdx.x;
    if (blk >= 2048) {                         // w2T: [4][1024][512] -> bf16 [4][512][1024]
        int m = blk - 2048;
        int bx = m & 15, by = (m >> 4) & 31, slice = m >> 9;
        int c0 = bx * 32, r0 = by * 32;
        int cc = tid & 31, r8 = tid >> 5;
        const float* ip = w2 + (size_t)slice * 524288;
        unsigned short* op = w2T + (size_t)slice * 524288;
        #pragma unroll
        for (int k = 0; k < 4; ++k) {
            int r = r8 + k * 8;
            tsh[r][cc] = ip[(size_t)(r0 + r) * 512 + c0 + cc];
        }
        __syncthreads();
        #pragma unroll
        for (int k = 0; k < 4; ++k) {
            int rr = r8 + k * 8;
            op[(size_t)(c0 + rr) * 1024 + r0 + cc] = f2bf(tsh[cc][rr]);
        }
        return;
    }
    int b = blk >> 10, i = blk & 1023;
    const float4* dp = (const float4*)(h1 + ((size_t)b * 3072 + i) * SDIM);
    const float4* sp = (const float4*)(h1 + ((size_t)b * 3072 + 1024 + i) * SDIM);
    const float4* hp = (const float4*)(h1 + ((size_t)b * 3072 + 2048 + i) * SDIM);
    float4 v = dp[tid];
    float c0 = v.x, c1 = c0 + v.y, c2 = c1 + v.z, c3 = c2 + v.w;
    int lane = tid & 63, w = tid >> 6;
    float sc = c3;
    #pragma unroll
    for (int off = 1; off < 64; off <<= 1) {
        float p = __shfl_up(sc, off);
        if (lane >= off) sc += p;
    }
    if (lane == 63) wsum[w] = sc;
    __syncthreads();
    float wbase = 0.f;
    #pragma unroll
    for (int ww = 0; ww < 4; ++ww)
        if (ww < w) wbase += wsum[ww];
    float base = wbase + sc - c3;
    float4 scv = sp[tid], sh = hp[tid];
    float4 dv = ((const float4*)divisor)[tid];
    float4 o;
    o.x = (base + c0) / dv.x * scv.x + sh.x;
    o.y = (base + c1) / dv.y * scv.y + sh.y;
    o.z = (base + c2) / dv.z * scv.z + sh.z;
    o.w = (base + c3) / dv.w * scv.w + sh.w;
    ((float4*)(y + ((size_t)b * 1024 + i) * SDIM))[tid] = o;
}

// ---------------- norm0: channel norm + leaky, split bf16 out [b][s][i] --------------
__global__ __launch_bounds__(256) void norm0_kernel(
    const float* __restrict__ g, unsigned short* __restrict__ oh,
    unsigned short* __restrict__ ol)
{
    int blk = blockIdx.x;
    int b = blk >> 7;
    int s0 = (blk & 127) * 8;
    int tid = threadIdx.x;
    int sg = tid & 7, grp = tid >> 3;
    int s = s0 + sg;
    const float* bp = g + ((size_t)b * 1024) * SDIM + s;
    float v[32];
    float sum = 0.f, ssq = 0.f;
    #pragma unroll
    for (int j = 0; j < 32; ++j) {
        float x = bp[(size_t)(grp * 32 + j) * SDIM];
        v[j] = x; sum += x; ssq += x * x;
    }
    __shared__ float rs[32][8], rq[32][8], stat[2][8];
    rs[grp][sg] = sum; rq[grp][sg] = ssq;
    __syncthreads();
    for (int h = 16; h >= 1; h >>= 1) {
        if (grp < h) { rs[grp][sg] += rs[grp + h][sg]; rq[grp][sg] += rq[grp + h][sg]; }
        __syncthreads();
    }
    if (grp == 0) {
        float S1 = rs[0][sg], S2 = rq[0][sg];
        float mean = S1 * (1.0f / 1024.0f);
        float ssc = fmaxf(S2 - 1024.0f * mean * mean, 0.0f);
        stat[0][sg] = mean;
        stat[1][sg] = 1.0f / (sqrtf(ssc) * (1.0f / 32.0f) + 1e-5f);
    }
    __syncthreads();
    float mean = stat[0][sg], inv = stat[1][sg];
    size_t tbase = (((size_t)b << 10) + s) * 1024 + grp * 32;
    #pragma unroll
    for (int j0 = 0; j0 < 32; j0 += 4) {
        unsigned short uh[4], ul[4];
        #pragma unroll
        for (int jj = 0; jj < 4; ++jj) {
            float o = (v[j0 + jj] - mean) * inv;
            o = (o >= 0.f) ? o : 0.02f * o;
            uh[jj] = f2bf(o);
            ul[jj] = f2bf(o - bf2f(uh[jj]));
        }
        *(ushort4*)(oh + tbase + j0) = (ushort4){uh[0], uh[1], uh[2], uh[3]};
        *(ushort4*)(ol + tbase + j0) = (ushort4){ul[0], ul[1], ul[2], ul[3]};
    }
}

// --- normgate: gated combine + norm + leaky + gate2; reads TRANSPOSED h1T[b][s][3072]
__global__ __launch_bounds__(256) void normgate_kernel(
    const float* __restrict__ h1T, const float* __restrict__ wg,
    unsigned short* __restrict__ outT, int* __restrict__ idx, float* __restrict__ acc)
{
    int blk = blockIdx.x;
    int b = blk >> 7;
    int s0 = (blk & 127) * 8;
    int tid = threadIdx.x;
    int sg = tid & 7, grp = tid >> 3;
    int s = s0 + sg;
    const float* row = h1T + ((size_t)((b << 10) + s)) * 3072;
    float v[32];
    float sum = 0.f, ssq = 0.f;
    #pragma unroll
    for (int j0 = 0; j0 < 32; j0 += 4) {
        int i = grp * 32 + j0;
        float4 av = *(const float4*)(row + i);
        float4 mv = *(const float4*)(row + 1024 + i);
        float4 dv = *(const float4*)(row + 2048 + i);
        float x0 = av.x * mv.x + dv.x;
        float x1 = av.y * mv.y + dv.y;
        float x2 = av.z * mv.z + dv.z;
        float x3 = av.w * mv.w + dv.w;
        v[j0] = x0; v[j0 + 1] = x1; v[j0 + 2] = x2; v[j0 + 3] = x3;
        sum += x0 + x1 + x2 + x3;
        ssq += x0 * x0 + x1 * x1 + x2 * x2 + x3 * x3;
    }
    __shared__ float rs[32][8], rq[32][8], stat[2][8];
    rs[grp][sg] = sum; rq[grp][sg] = ssq;
    __syncthreads();
    for (int h = 16; h >= 1; h >>= 1) {
        if (grp < h) { rs[grp][sg] += rs[grp + h][sg]; rq[grp][sg] += rq[grp + h][sg]; }
        __syncthreads();
    }
    if (grp == 0) {
        float S1 = rs[0][sg], S2 = rq[0][sg];
        float mean = S1 * (1.0f / 1024.0f);
        float ssc = fmaxf(S2 - 1024.0f * mean * mean, 0.0f);
        stat[0][sg] = mean;
        stat[1][sg] = 1.0f / (sqrtf(ssc) * (1.0f / 32.0f) + 1e-5f);
    }
    __syncthreads();
    float mean = stat[0][sg], inv = stat[1][sg];
    float l0 = 0.f, l1 = 0.f, l2 = 0.f, l3 = 0.f;
    size_t tbase = (((size_t)b << 10) + s) * 1024 + grp * 32;
    #pragma unroll
    for (int j0 = 0; j0 < 32; j0 += 4) {
        unsigned short u[4];
        #pragma unroll
        for (int jj = 0; jj < 4; ++jj) {
            int i = grp * 32 + j0 + jj;
            float o = (v[j0 + jj] - mean) * inv;
            o = (o >= 0.f) ? o : 0.02f * o;
            u[jj] = f2bf(o);
            l0 += o * wg[i];
            l1 += o * wg[1024 + i];
            l2 += o * wg[2048 + i];
            l3 += o * wg[3072 + i];
        }
        *(ushort4*)(outT + tbase + j0) = (ushort4){u[0], u[1], u[2], u[3]};
    }
    __shared__ float pl[4][32][8];
    __shared__ float la[8];
    pl[0][grp][sg] = l0; pl[1][grp][sg] = l1;
    pl[2][grp][sg] = l2; pl[3][grp][sg] = l3;
    if (tid < 8) la[tid] = 0.f;
    __syncthreads();
    for (int h = 16; h >= 1; h >>= 1) {
        if (grp < h) {
            #pragma unroll
            for (int e = 0; e < 4; ++e) pl[e][grp][sg] += pl[e][grp + h][sg];
        }
        __syncthreads();
    }
    if (grp == 0) {
        float L[4] = {pl[0][0][sg], pl[1][0][sg], pl[2][0][sg], pl[3][0][sg]};
        float m = fmaxf(fmaxf(L[0], L[1]), fmaxf(L[2], L[3]));
        float e0 = expf(L[0] - m), e1 = expf(L[1] - m), e2 = expf(L[2] - m), e3 = expf(L[3] - m);
        float invs = 1.0f / (e0 + e1 + e2 + e3);
        int best = 0; float bv = L[0];
        if (L[1] > bv) { bv = L[1]; best = 1; }
        if (L[2] > bv) { bv = L[2]; best = 2; }
        if (L[3] > bv) { bv = L[3]; best = 3; }
        idx[(b << 10) + s] = best;
        atomicAdd(&la[0], e0 * invs);
        atomicAdd(&la[1], e1 * invs);
        atomicAdd(&la[2], e2 * invs);
        atomicAdd(&la[3], e3 * invs);
        atomicAdd(&la[4 + best], 1.0f);
    }
    __syncthreads();
    if (tid < 8) atomicAdd(&acc[8 + tid], la[tid]);
}

extern "C" void kernel_launch(void* const* d_in, const int* in_sizes, int n_in,
                              void* d_out, int out_size, void* d_ws, size_t ws_size,
                              hipStream_t stream) {
    const float* inp     = (const float*)d_in[0];
    const float* divisor = (const float*)d_in[1];
    const float* w0_gate = (const float*)d_in[2];
    const float* w0      = (const float*)d_in[3];
    const float* w1      = (const float*)d_in[4];
    const float* w2_gate = (const float*)d_in[5];
    const float* w2      = (const float*)d_in[6];
    float* out = (float*)d_out;
    (void)in_sizes; (void)n_in; (void)out_size; (void)ws_size;

    char* ws = (char*)d_ws;
    const unsigned short* base = (const unsigned short*)ws;

    float* h1            = (float*)(ws + 0);                  // 25165824 (also h1T)
    float* g             = (float*)(ws + 25165824);           //  8388608
    unsigned short* gT1h = (unsigned short*)(ws + 33554432);  //  4194304
    unsigned short* gT1l = (unsigned short*)(ws + 37748736);  //  4194304
    unsigned short* w1Th = (unsigned short*)(ws + 41943040);  // 18874368
    unsigned short* w1Tl = (unsigned short*)(ws + 60817408);  // 18874368
    unsigned short* xTh  = (unsigned short*)(ws + 79691776);  //  2097152
    unsigned short* xTl  = (unsigned short*)(ws + 81788928);  //  2097152
    unsigned short* w0Th = (unsigned short*)(ws + 83886080);  // 12582912
    unsigned short* w0Tl = (unsigned short*)(ws + 96468992);  // 12582912
    unsigned short* gT2  = (unsigned short*)(ws + 79691776);  //  4194304 (reuse)
    unsigned short* w2T  = (unsigned short*)(ws + 83886080);  //  4194304 (reuse)
    int* idx1            = (int*)(ws + 109051904);
    int* idx2            = (int*)(ws + 109060096);
    float* acc           = (float*)(ws + 109068288);
    int* perm1           = (int*)(ws + 109076480);
    int* eSort1          = (int*)(ws + 109084672);
    int* perm2           = (int*)(ws + 109092864);
    int* eSort2          = (int*)(ws + 109101056);
    float* zbuf          = (float*)(ws + 109109248);          // 4096 B zeros

    const unsigned int GT1H = 16777216u, GT1L = 18874368u;
    const unsigned int W1TH = 20971520u, W1TL = 30408704u;
    const unsigned int XTH  = 39845888u, XTL  = 40894464u;
    const unsigned int W0TH = 41943040u, W0TL = 48234496u;
    const unsigned int ZB   = 54554624u;                      // zbuf in ushort units

    hipMemsetAsync(acc, 0, 64, stream);
    hipMemsetAsync(zbuf, 0, 4096, stream);

    // fused prep: xT/w0T split transposes + w1 split cvt + gate1
    prep_kernel<<<19712, 256, 0, stream>>>(inp, w0, w1, xTh, xTl, w0Th, w0Tl,
                                           w1Th, w1Tl, w0_gate, idx1, acc);

    sort_kernel<<<2, 1024, 0, stream>>>(idx1, perm1, eSort1);
    // MoE 1 (split), 768-thread 12-wave dbuf
    moe_split_kernel<<<256, 768, 163840, stream>>>(base, XTH, XTL, W0TH, W0TL, perm1, eSort1, h1);

    // cumsum + affine (shfl scan) fused with w2T transpose
    cumsum_w2t_kernel<<<4096, 256, 0, stream>>>(h1, divisor, g, w2, w2T);
    norm0_kernel<<<256, 256, 0, stream>>>(g, gT1h, gT1l);
    // conv (split), 512-thread 8-wave dbuf (fm=6/fn=2), transposed output h1T
    conv_split_kernel<<<256, 512, 141312, stream>>>(base, GT1H, GT1L, W1TH, W1TL, ZB, h1);
    // fused gated-combine + norm + leaky + gate2 (reads h1T)
    normgate_kernel<<<256, 256, 0, stream>>>(h1, w2_gate, gT2, idx2, acc);

    // MoE 2 (plain bf16) + fused loss
    sort_kernel<<<2, 1024, 0, stream>>>(idx2, perm2, eSort2);
    moe_kernel<<<128, 256, 0, stream>>>(gT2, w2T, perm2, eSort2, out, 1024, 512, acc);
}

// Round 19
// 232.577 us; speedup vs baseline: 1.0767x; 1.0024x over previous
//
#include <hip/hip_runtime.h>
#include <hip/hip_bf16.h>

#define SDIM 1024

typedef float f32x4 __attribute__((ext_vector_type(4)));
typedef short short8 __attribute__((ext_vector_type(8)));

__device__ __forceinline__ unsigned short f2bf(float f) {
    __hip_bfloat16 h = __float2bfloat16(f);
    return *reinterpret_cast<unsigned short*>(&h);
}
__device__ __forceinline__ float bf2f(unsigned short u) {
    return __uint_as_float(((unsigned int)u) << 16);
}
__device__ __forceinline__ void gload_lds16(const unsigned short* g, unsigned short* l) {
    __builtin_amdgcn_global_load_lds((const __attribute__((address_space(1))) void*)g,
                                     (__attribute__((address_space(3))) void*)l, 16, 0, 0);
}

// ------- split-transpose body (uniform branch per block) -------
__device__ __forceinline__ void tr_split(
    const float* __restrict__ in, unsigned short* __restrict__ oh,
    unsigned short* __restrict__ ol, int R, int C, size_t sliceStride,
    int bx, int by, int slice, int tid, float (*t)[33])
{
    int c0 = bx * 32, r0 = by * 32;
    int cc = tid & 31, r8 = tid >> 5;
    const float* ip = in + slice * sliceStride;
    #pragma unroll
    for (int k = 0; k < 4; ++k) {
        int r = r8 + k * 8;
        t[r][cc] = ip[(size_t)(r0 + r) * C + c0 + cc];
    }
    __syncthreads();
    #pragma unroll
    for (int k = 0; k < 4; ++k) {
        int rr = r8 + k * 8;
        float v = t[cc][rr];
        unsigned short hi = f2bf(v);
        unsigned short lo = f2bf(v - bf2f(hi));
        size_t o = slice * sliceStride + (size_t)(c0 + rr) * R + r0 + cc;
        oh[o] = hi; ol[o] = lo;
    }
}

// ---- mega-prep: xT split + w0T split + w1cvt + gate1 (independent block ranges) ----
__global__ __launch_bounds__(256) void prep_kernel(
    const float* __restrict__ inp, const float* __restrict__ w0,
    const float* __restrict__ w1,
    unsigned short* __restrict__ xTh, unsigned short* __restrict__ xTl,
    unsigned short* __restrict__ w0Th, unsigned short* __restrict__ w0Tl,
    unsigned short* __restrict__ w1Th, unsigned short* __restrict__ w1Tl,
    const float* __restrict__ wg, int* __restrict__ idx, float* __restrict__ acc)
{
    __shared__ float t[32][33];
    __shared__ float wgs[4 * 512];
    __shared__ float part[32][4][9];
    __shared__ float la[8];
    int id = blockIdx.x;
    int tid = threadIdx.x;
    if (id < 1024) {                       // xT: [2][512][1024] -> split [2][1024][512]
        int bx = id & 31, by = (id >> 5) & 15, slice = id >> 9;
        tr_split(inp, xTh, xTl, 512, 1024, (size_t)512 * 1024, bx, by, slice, tid, t);
    } else if (id < 7168) {                // w0T: [4][512][3072] -> split [4][3072][512]
        int m = id - 1024;
        int bx = m % 96, by = (m / 96) & 15, slice = m / 1536;
        tr_split(w0, w0Th, w0Tl, 512, 3072, (size_t)512 * 3072, bx, by, slice, tid, t);
    } else if (id < 19456) {               // w1: [3072][1024][3] -> split [3][3072][1024]
        int tt = (id - 7168) * 256 + tid;
        int o = tt >> 10, i = tt & 1023;
        const float* p = w1 + (size_t)o * 3072 + i * 3;
        #pragma unroll
        for (int k = 0; k < 3; ++k) {
            float v = p[k];
            unsigned short hi = f2bf(v);
            unsigned short lo = f2bf(v - bf2f(hi));
            size_t off = (size_t)k * 3145728 + (size_t)o * 1024 + i;
            w1Th[off] = hi; w1Tl[off] = lo;
        }
    } else {                               // gate1: 256 blocks, 8 tokens each
        if (tid < 8) la[tid] = 0.f;
        for (int l = tid; l < 2048; l += 256) wgs[l] = wg[l];
        __syncthreads();
        int t0 = (id - 19456) * 8;
        int b = t0 >> 10, s0 = t0 & 1023;
        int sl = tid & 7, fg = tid >> 3;
        float l0 = 0.f, l1 = 0.f, l2 = 0.f, l3 = 0.f;
        for (int f = fg; f < 512; f += 32) {
            float xv = inp[((size_t)b * 512 + f) * SDIM + s0 + sl];
            l0 += xv * wgs[f];
            l1 += xv * wgs[512 + f];
            l2 += xv * wgs[1024 + f];
            l3 += xv * wgs[1536 + f];
        }
        part[fg][0][sl] = l0; part[fg][1][sl] = l1;
        part[fg][2][sl] = l2; part[fg][3][sl] = l3;
        __syncthreads();
        for (int h = 16; h >= 1; h >>= 1) {
            if (fg < h) {
                #pragma unroll
                for (int e = 0; e < 4; ++e) part[fg][e][sl] += part[fg + h][e][sl];
            }
            __syncthreads();
        }
        if (fg == 0) {
            float L[4] = {part[0][0][sl], part[0][1][sl], part[0][2][sl], part[0][3][sl]};
            float m = fmaxf(fmaxf(L[0], L[1]), fmaxf(L[2], L[3]));
            float e0 = expf(L[0] - m), e1 = expf(L[1] - m), e2 = expf(L[2] - m), e3 = expf(L[3] - m);
            float inv = 1.0f / (e0 + e1 + e2 + e3);
            int best = 0; float bv = L[0];
            if (L[1] > bv) { bv = L[1]; best = 1; }
            if (L[2] > bv) { bv = L[2]; best = 2; }
            if (L[3] > bv) { bv = L[3]; best = 3; }
            idx[t0 + sl] = best;
            atomicAdd(&la[0], e0 * inv);
            atomicAdd(&la[1], e1 * inv);
            atomicAdd(&la[2], e2 * inv);
            atomicAdd(&la[3], e3 * inv);
            atomicAdd(&la[4 + best], 1.0f);
        }
        __syncthreads();
        if (tid < 8) atomicAdd(&acc[tid], la[tid]);
    }
}

// ---------------- token sort: deterministic ballot counting sort per batch ----------
__global__ __launch_bounds__(1024) void sort_kernel(
    const int* __restrict__ idx, int* __restrict__ perm, int* __restrict__ eSorted)
{
    int b = blockIdx.x;
    int tid = threadIdx.x;
    int lane = tid & 63, w = tid >> 6;      // 16 waves
    int e = idx[(b << 10) + tid];
    __shared__ int wcnt[16][4];
    __shared__ int woff[16][4];
    int r = 0;
    unsigned long long lt = (1ull << lane) - 1ull;
    #pragma unroll
    for (int eo = 0; eo < 4; ++eo) {
        unsigned long long m = __ballot(e == eo);
        if (lane == 0) wcnt[w][eo] = __popcll(m);
        if (e == eo) r = __popcll(m & lt);
    }
    __syncthreads();
    if (tid == 0) {
        int baseAcc = 0;
        for (int eo = 0; eo < 4; ++eo)
            for (int ww = 0; ww < 16; ++ww) { woff[ww][eo] = baseAcc; baseAcc += wcnt[ww][eo]; }
    }
    __syncthreads();
    int pos = woff[w][e] + r;
    perm[(b << 10) + pos] = tid;
    eSorted[(b << 10) + pos] = e;
}

// ---- MoE1 split-bf16 MFMA, 96d x 256tok, 768 thr (12 waves of 32d x 64t), dbuf ----
// Per buffer rows(64B): Xh[0,256) Xl[256,512) Wh[512,896) Wl[896,1280); 80 segs
__global__ __launch_bounds__(768) void moe_split_kernel(
    const unsigned short* __restrict__ base, unsigned int XH, unsigned int XL,
    unsigned int WH, unsigned int WL,
    const int* __restrict__ perm, const int* __restrict__ eSorted,
    float* __restrict__ out)
{
    extern __shared__ unsigned short lds[];    // 2 x 40960 ushorts = 160 KiB
    const int BUF = 40960;
    int id = blockIdx.x;
    int wg = (id & 7) * 32 + (id >> 3);        // 256 blocks, XCD-contiguous
    int t0 = (wg & 7) * 256;                   // token fastest -> W L2-resident per XCD
    int d0 = (wg >> 3) * 96;
    int b = t0 >> 10, s0 = t0 & 1023;
    int tid = threadIdx.x;
    int lane = tid & 63;
    int lm = lane & 15, q = lane >> 4;
    int wid = tid >> 6;                        // 0..11
    int wm = (wid >> 2) * 32, wn = (wid & 3) * 64;

    int eLo = eSorted[(b << 10) + s0];
    int eHi = eSorted[(b << 10) + s0 + 255];

    unsigned int gofs[7];
    int lofs[7], doSeg[7];
    #pragma unroll
    for (int j = 0; j < 7; ++j) {
        int seg = wid + 12 * j;                // 0..83; valid < 80
        gofs[j] = 0; lofs[j] = 0; doSeg[j] = 0;
        if (seg < 80) {
            int row = seg * 16 + (lane >> 2);
            int slot = lane & 3;
            int c = slot ^ ((row >> 1) & 3);
            unsigned int src;
            int act = 1;
            if (row < 512) {
                int gr = (row < 256) ? row : row - 256;
                unsigned int hb = (row < 256) ? XH : XL;
                int tj = perm[(b << 10) + s0 + gr];
                src = hb + (unsigned int)(((b << 10) + tj) * 512) + c * 8;
            } else {
                int R = row - 512;
                unsigned int hb = WH;
                if (R >= 384) { R -= 384; hb = WL; }
                int e = R / 96, dl = R - e * 96;
                act = (e >= eLo && e <= eHi) ? 1 : 0;
                src = hb + (unsigned int)((e * 3072 + d0 + dl) * 512) + c * 8;
            }
            gofs[j] = src;
            lofs[j] = seg * 512 + lane * 8;
            doSeg[j] = act;
        }
    }

    int bofH[4];
    #pragma unroll
    for (int fn = 0; fn < 4; ++fn) {
        int row = wn + fn * 16 + lm;           // 0..255
        bofH[fn] = row * 32 + ((q ^ ((row >> 1) & 3)) << 3);
    }
    int aofH[4][2];
    #pragma unroll
    for (int e = 0; e < 4; ++e)
        #pragma unroll
        for (int fm = 0; fm < 2; ++fm) {
            int row = 512 + e * 96 + wm + fm * 16 + lm;
            aofH[e][fm] = row * 32 + ((q ^ ((row >> 1) & 3)) << 3);
        }
    // lo offsets: Xl = +256 rows (+8192), Wl = +384 rows (+12288); swizzle class preserved

    int eidx[4], sv[4];
    #pragma unroll
    for (int fn = 0; fn < 4; ++fn) {
        int sl = (b << 10) + s0 + wn + fn * 16 + lm;
        eidx[fn] = eSorted[sl];
        sv[fn]   = perm[sl];
    }
    bool presF[4][4], presE[4];
    #pragma unroll
    for (int e = 0; e < 4; ++e) {
        presE[e] = false;
        #pragma unroll
        for (int fn = 0; fn < 4; ++fn) {
            presF[e][fn] = __any(eidx[fn] == e);
            presE[e] = presE[e] || presF[e][fn];
        }
    }

    f32x4 acc[2][4];
    #pragma unroll
    for (int fm = 0; fm < 2; ++fm)
        #pragma unroll
        for (int fn = 0; fn < 4; ++fn)
            acc[fm][fn] = (f32x4){0.f, 0.f, 0.f, 0.f};

    const short8 z = {0, 0, 0, 0, 0, 0, 0, 0};

    // prologue: first K-slice DMA into buffer 0
    #pragma unroll
    for (int j = 0; j < 7; ++j)
        if (doSeg[j]) gload_lds16(base + gofs[j], lds + lofs[j]);

    int curOfs = 0;
    for (int f0 = 0; f0 < 512; f0 += 32) {
        __syncthreads();                       // drains DMA for buf[cur]; syncs prev reads
        int nxtOfs = curOfs ^ BUF;
        if (f0 + 32 < 512) {                   // prefetch next K-slice into other buffer
            #pragma unroll
            for (int j = 0; j < 7; ++j)
                if (doSeg[j]) gload_lds16(base + gofs[j] + f0 + 32, lds + nxtOfs + lofs[j]);
        }

        const unsigned short* lb = lds + curOfs;
        short8 bh[4], bl[4];
        #pragma unroll
        for (int fn = 0; fn < 4; ++fn) {
            bh[fn] = *(const short8*)(lb + bofH[fn]);
            bl[fn] = *(const short8*)(lb + bofH[fn] + 8192);
        }
        #pragma unroll
        for (int e = 0; e < 4; ++e) {
            if (presE[e]) {
                short8 ah[2], al[2];
                #pragma unroll
                for (int fm = 0; fm < 2; ++fm) {
                    ah[fm] = *(const short8*)(lb + aofH[e][fm]);
                    al[fm] = *(const short8*)(lb + aofH[e][fm] + 12288);
                }
                __builtin_amdgcn_s_setprio(1);
                #pragma unroll
                for (int fn = 0; fn < 4; ++fn) {
                    if (presF[e][fn]) {
                        short8 bmH = (eidx[fn] == e) ? bh[fn] : z;
                        short8 bmL = (eidx[fn] == e) ? bl[fn] : z;
                        #pragma unroll
                        for (int fm = 0; fm < 2; ++fm) {
                            acc[fm][fn] = __builtin_amdgcn_mfma_f32_16x16x32_bf16(ah[fm], bmH, acc[fm][fn], 0, 0, 0);
                            acc[fm][fn] = __builtin_amdgcn_mfma_f32_16x16x32_bf16(ah[fm], bmL, acc[fm][fn], 0, 0, 0);
                            acc[fm][fn] = __builtin_amdgcn_mfma_f32_16x16x32_bf16(al[fm], bmH, acc[fm][fn], 0, 0, 0);
                        }
                    }
                }
                __builtin_amdgcn_s_setprio(0);
            }
        }
        curOfs = nxtOfs;
    }

    #pragma unroll
    for (int fm = 0; fm < 2; ++fm)
        #pragma unroll
        for (int fn = 0; fn < 4; ++fn) {
            int d = d0 + wm + fm * 16 + q * 4;
            float* op = out + ((size_t)b * 3072 + d) * SDIM + sv[fn];
            #pragma unroll
            for (int r = 0; r < 4; ++r)
                op[(size_t)r * SDIM] = acc[fm][fn][r];
        }
}

// ---- conv1d K=3 split-bf16, 96o x 256tok, 1024 thr (16 waves of 48o x 32t), dbuf ---
// Output TRANSPOSED: h1T[b][s][3072].  Per buffer rows(64B): Gh[0,264) Gl[264,528)
// Wh[528,816) Wl[816,1104); 69 segs
__global__ __launch_bounds__(1024) void conv_split_kernel(
    const unsigned short* __restrict__ base, unsigned int GH, unsigned int GL,
    unsigned int WH, unsigned int WL, unsigned int ZB, float* __restrict__ h1T)
{
    extern __shared__ unsigned short lds[];    // 2 x 35328 ushorts = 138 KiB
    const int BUF = 35328;
    int id = blockIdx.x;
    int wg = (id & 7) * 32 + (id >> 3);        // 256 blocks, XCD-contiguous
    int t0 = (wg & 7) * 256;                   // token fastest -> W L2-resident per XCD
    int o0 = (wg >> 3) * 96;
    int b = t0 >> 10, s0 = t0 & 1023;
    int tid = threadIdx.x;
    int lane = tid & 63;
    int lm = lane & 15, q = lane >> 4;
    int wid = tid >> 6;                        // 0..15
    int wm = (wid >> 3) * 48, wn = (wid & 7) * 32;

    unsigned int gofs[5];
    int lofs[5];
    int nseg = (wid < 5) ? 5 : 4;              // 69 segs over 16 waves
    #pragma unroll
    for (int j = 0; j < 5; ++j) {
        int seg = wid + 16 * j;
        gofs[j] = ZB; lofs[j] = 0;
        if (seg < 69) {
            int row = seg * 16 + (lane >> 2);
            int slot = lane & 3;
            int c = slot ^ ((row >> 1) & 3);
            unsigned int src;
            if (row < 528) {
                int gr = (row < 264) ? row : row - 264;
                unsigned int hb = (row < 264) ? GH : GL;
                int s = s0 - 2 + gr;
                if (s < 0) src = ZB + c * 8;                       // causal pad -> zeros
                else { if (s > 1023) s = 1023;                     // tail rows never read
                       src = hb + ((unsigned int)((b << 10) + s) << 10) + c * 8; }
            } else {
                int R = row - 528;
                unsigned int hb = WH;
                if (R >= 288) { R -= 288; hb = WL; }
                int k = R / 96, ol = R - k * 96;
                src = hb + (unsigned int)k * 3145728u + ((unsigned int)(o0 + ol) << 10) + c * 8;
            }
            gofs[j] = src;
            lofs[j] = seg * 512 + lane * 8;
        }
    }

    int aofH[3][3], aofL[3][3], bofH[3][2], bofL[3][2];
    #pragma unroll
    for (int k = 0; k < 3; ++k) {
        #pragma unroll
        for (int fm = 0; fm < 3; ++fm) {
            int R = k * 96 + wm + fm * 16 + lm;
            int rh = 528 + R, rl = 816 + R;
            aofH[k][fm] = rh * 32 + ((q ^ ((rh >> 1) & 3)) << 3);
            aofL[k][fm] = rl * 32 + ((q ^ ((rl >> 1) & 3)) << 3);
        }
        #pragma unroll
        for (int fn = 0; fn < 2; ++fn) {
            int rh = wn + fn * 16 + lm + k;     // tile row = s - s0 + 2, max 257
            int rl = rh + 264;
            bofH[k][fn] = rh * 32 + ((q ^ ((rh >> 1) & 3)) << 3);
            bofL[k][fn] = rl * 32 + ((q ^ ((rl >> 1) & 3)) << 3);
        }
    }

    f32x4 acc[3][2];
    #pragma unroll
    for (int fm = 0; fm < 3; ++fm)
        #pragma unroll
        for (int fn = 0; fn < 2; ++fn)
            acc[fm][fn] = (f32x4){0.f, 0.f, 0.f, 0.f};

    // prologue: issue first-tile DMA into buffer 0
    #pragma unroll
    for (int j = 0; j < 5; ++j)
        if (j < nseg) gload_lds16(base + gofs[j], lds + lofs[j]);

    int curOfs = 0;
    for (int i0 = 0; i0 < 1024; i0 += 32) {
        __syncthreads();                       // drains DMA for buf[cur]; syncs prev reads
        int nxtOfs = curOfs ^ BUF;
        if (i0 + 32 < 1024) {                  // prefetch next tile into other buffer
            #pragma unroll
            for (int j = 0; j < 5; ++j)
                if (j < nseg) gload_lds16(base + gofs[j] + i0 + 32, lds + nxtOfs + lofs[j]);
        }

        const unsigned short* lb = lds + curOfs;
        #pragma unroll
        for (int k = 0; k < 3; ++k) {
            short8 ah[3], al[3], bh[2], bl[2];
            #pragma unroll
            for (int fm = 0; fm < 3; ++fm) {
                ah[fm] = *(const short8*)(lb + aofH[k][fm]);
                al[fm] = *(const short8*)(lb + aofL[k][fm]);
            }
            #pragma unroll
            for (int fn = 0; fn < 2; ++fn) {
                bh[fn] = *(const short8*)(lb + bofH[k][fn]);
                bl[fn] = *(const short8*)(lb + bofL[k][fn]);
            }
            __builtin_amdgcn_s_setprio(1);
            #pragma unroll
            for (int fm = 0; fm < 3; ++fm)
                #pragma unroll
                for (int fn = 0; fn < 2; ++fn) {
                    acc[fm][fn] = __builtin_amdgcn_mfma_f32_16x16x32_bf16(ah[fm], bh[fn], acc[fm][fn], 0, 0, 0);
                    acc[fm][fn] = __builtin_amdgcn_mfma_f32_16x16x32_bf16(ah[fm], bl[fn], acc[fm][fn], 0, 0, 0);
                    acc[fm][fn] = __builtin_amdgcn_mfma_f32_16x16x32_bf16(al[fm], bh[fn], acc[fm][fn], 0, 0, 0);
                }
            __builtin_amdgcn_s_setprio(0);
        }
        curOfs = nxtOfs;
    }

    // transposed epilogue: one f32x4 store per fragment (o contiguous)
    #pragma unroll
    for (int fm = 0; fm < 3; ++fm)
        #pragma unroll
        for (int fn = 0; fn < 2; ++fn) {
            int o = o0 + wm + fm * 16 + q * 4;
            int s = s0 + wn + fn * 16 + lm;
            *(f32x4*)(h1T + ((size_t)((b << 10) + s)) * 3072 + o) = acc[fm][fn];
        }
}

// ---------------- MoE2 plain-bf16 MFMA + fused loss, 64d x 128 sorted tokens --------
// LDS rows(64B): X[0,128) W[128,384); 24 segs of 16 rows
__global__ __launch_bounds__(256) void moe_kernel(
    const unsigned short* __restrict__ xT, const unsigned short* __restrict__ wT,
    const int* __restrict__ perm, const int* __restrict__ eSorted,
    float* __restrict__ out, int Fdim, int Ddim, const float* __restrict__ accv)
{
    if (blockIdx.x == 0 && threadIdx.x == 0) {     // fused loss (acc final pre-launch)
        float l = 0.f;
        #pragma unroll
        for (int e = 0; e < 4; ++e)
            l += accv[e] * accv[4 + e] + accv[8 + e] * accv[12 + e];
        out[2 * 512 * 1024] = l * (1.0f / (2048.0f * 2048.0f));
    }
    __shared__ unsigned short lds[384 * 32];   // 24 KiB
    int id = blockIdx.x;
    int chunk = gridDim.x >> 3;
    int wg = (id & 7) * chunk + (id >> 3);
    int t0 = (wg & 15) * 128;
    int d0 = (wg >> 4) * 64;
    int b = t0 >> 10, s0 = t0 & 1023;
    int tid = threadIdx.x;
    int lane = tid & 63, wid = tid >> 6;
    int lm = lane & 15, q = lane >> 4;
    int wm = (wid >> 1) * 32, wn = (wid & 1) * 64;

    int eLo = eSorted[(b << 10) + s0];
    int eHi = eSorted[(b << 10) + s0 + 127];

    const unsigned short* gsrc[6];
    int lofs[6], doSeg[6];
    #pragma unroll
    for (int j = 0; j < 6; ++j) {
        int seg = wid + 4 * j;                 // 0..23
        int row = seg * 16 + (lane >> 2);
        int slot = lane & 3;
        int c = slot ^ ((row >> 1) & 3);
        int act = 1;
        const unsigned short* src;
        if (row < 128) {
            int tj = perm[(b << 10) + s0 + row];
            src = xT + (size_t)((b << 10) + tj) * Fdim + c * 8;
        } else {
            int R = row - 128;                 // e*64 + dl
            int e = R >> 6;
            act = (e >= eLo && e <= eHi) ? 1 : 0;
            src = wT + (size_t)(e * Ddim + d0 + (R & 63)) * Fdim + c * 8;
        }
        gsrc[j] = src; lofs[j] = seg * 512 + lane * 8; doSeg[j] = act;
    }

    int bof[4], aof[4][2];
    #pragma unroll
    for (int fn = 0; fn < 4; ++fn) {
        int row = wn + fn * 16 + lm;
        bof[fn] = row * 32 + ((q ^ ((row >> 1) & 3)) << 3);
    }
    #pragma unroll
    for (int e = 0; e < 4; ++e)
        #pragma unroll
        for (int fm = 0; fm < 2; ++fm) {
            int R = 128 + e * 64 + wm + fm * 16 + lm;
            aof[e][fm] = R * 32 + ((q ^ ((R >> 1) & 3)) << 3);
        }

    int eidx[4], sv[4];
    #pragma unroll
    for (int fn = 0; fn < 4; ++fn) {
        int sl = (b << 10) + s0 + wn + fn * 16 + lm;
        eidx[fn] = eSorted[sl];
        sv[fn]   = perm[sl];
    }
    bool presF[4][4], presE[4];
    #pragma unroll
    for (int e = 0; e < 4; ++e) {
        presE[e] = false;
        #pragma unroll
        for (int fn = 0; fn < 4; ++fn) {
            presF[e][fn] = __any(eidx[fn] == e);
            presE[e] = presE[e] || presF[e][fn];
        }
    }

    f32x4 acc[2][4];
    #pragma unroll
    for (int fm = 0; fm < 2; ++fm)
        #pragma unroll
        for (int fn = 0; fn < 4; ++fn)
            acc[fm][fn] = (f32x4){0.f, 0.f, 0.f, 0.f};

    const short8 z = {0, 0, 0, 0, 0, 0, 0, 0};

    for (int f0 = 0; f0 < Fdim; f0 += 32) {
        __syncthreads();
        #pragma unroll
        for (int j = 0; j < 6; ++j)
            if (doSeg[j]) gload_lds16(gsrc[j] + f0, lds + lofs[j]);
        __syncthreads();

        short8 bf[4];
        #pragma unroll
        for (int fn = 0; fn < 4; ++fn)
            bf[fn] = *(const short8*)(lds + bof[fn]);
        #pragma unroll
        for (int e = 0; e < 4; ++e) {
            if (presE[e]) {
                short8 af[2];
                #pragma unroll
                for (int fm = 0; fm < 2; ++fm)
                    af[fm] = *(const short8*)(lds + aof[e][fm]);
                #pragma unroll
                for (int fn = 0; fn < 4; ++fn) {
                    if (presF[e][fn]) {
                        short8 bm = (eidx[fn] == e) ? bf[fn] : z;
                        #pragma unroll
                        for (int fm = 0; fm < 2; ++fm)
                            acc[fm][fn] = __builtin_amdgcn_mfma_f32_16x16x32_bf16(af[fm], bm, acc[fm][fn], 0, 0, 0);
                    }
                }
            }
        }
    }

    #pragma unroll
    for (int fm = 0; fm < 2; ++fm)
        #pragma unroll
        for (int fn = 0; fn < 4; ++fn) {
            int d = d0 + wm + fm * 16 + q * 4;
            float* op = out + ((size_t)b * Ddim + d) * SDIM + sv[fn];
            #pragma unroll
            for (int r = 0; r < 4; ++r)
                op[(size_t)r * SDIM] = acc[fm][fn][r];
        }
}

// ------ cumsum over s + affine (shfl scan) [blocks 0..2047] + w2T transpose [2048..4095]
__global__ __launch_bounds__(256) void cumsum_w2t_kernel(
    const float* __restrict__ h1, const float* __restrict__ divisor,
    float* __restrict__ y, const float* __restrict__ w2, unsigned short* __restrict__ w2T)
{
    __shared__ float tsh[32][33];
    __shared__ float wsum[4];
    int blk = blockIdx.x;
    int tid = threadIdx.x;
    if (blk >= 2048) {                         // w2T: [4][1024][512] -> bf16 [4][512][1024]
        int m = blk - 2048;
        int bx = m & 15, by = (m >> 4) & 31, slice = m >> 9;
        int c0 = bx * 32, r0 = by * 32;
        int cc = tid & 31, r8 = tid >> 5;
        const float* ip = w2 + (size_t)slice * 524288;
        unsigned short* op = w2T + (size_t)slice * 524288;
        #pragma unroll
        for (int k = 0; k < 4; ++k) {
            int r = r8 + k * 8;
            tsh[r][cc] = ip[(size_t)(r0 + r) * 512 + c0 + cc];
        }
        __syncthreads();
        #pragma unroll
        for (int k = 0; k < 4; ++k) {
            int rr = r8 + k * 8;
            op[(size_t)(c0 + rr) * 1024 + r0 + cc] = f2bf(tsh[cc][rr]);
        }
        return;
    }
    int b = blk >> 10, i = blk & 1023;
    const float4* dp = (const float4*)(h1 + ((size_t)b * 3072 + i) * SDIM);
    const float4* sp = (const float4*)(h1 + ((size_t)b * 3072 + 1024 + i) * SDIM);
    const float4* hp = (const float4*)(h1 + ((size_t)b * 3072 + 2048 + i) * SDIM);
    float4 v = dp[tid];
    float c0 = v.x, c1 = c0 + v.y, c2 = c1 + v.z, c3 = c2 + v.w;
    int lane = tid & 63, w = tid >> 6;
    float sc = c3;
    #pragma unroll
    for (int off = 1; off < 64; off <<= 1) {
        float p = __shfl_up(sc, off);
        if (lane >= off) sc += p;
    }
    if (lane == 63) wsum[w] = sc;
    __syncthreads();
    float wbase = 0.f;
    #pragma unroll
    for (int ww = 0; ww < 4; ++ww)
        if (ww < w) wbase += wsum[ww];
    float base = wbase + sc - c3;
    float4 scv = sp[tid], sh = hp[tid];
    float4 dv = ((const float4*)divisor)[tid];
    float4 o;
    o.x = (base + c0) / dv.x * scv.x + sh.x;
    o.y = (base + c1) / dv.y * scv.y + sh.y;
    o.z = (base + c2) / dv.z * scv.z + sh.z;
    o.w = (base + c3) / dv.w * scv.w + sh.w;
    ((float4*)(y + ((size_t)b * 1024 + i) * SDIM))[tid] = o;
}

// ---------------- norm0: channel norm + leaky, split bf16 out [b][s][i] --------------
__global__ __launch_bounds__(256) void norm0_kernel(
    const float* __restrict__ g, unsigned short* __restrict__ oh,
    unsigned short* __restrict__ ol)
{
    int blk = blockIdx.x;
    int b = blk >> 7;
    int s0 = (blk & 127) * 8;
    int tid = threadIdx.x;
    int sg = tid & 7, grp = tid >> 3;
    int s = s0 + sg;
    const float* bp = g + ((size_t)b * 1024) * SDIM + s;
    float v[32];
    float sum = 0.f, ssq = 0.f;
    #pragma unroll
    for (int j = 0; j < 32; ++j) {
        float x = bp[(size_t)(grp * 32 + j) * SDIM];
        v[j] = x; sum += x; ssq += x * x;
    }
    __shared__ float rs[32][8], rq[32][8], stat[2][8];
    rs[grp][sg] = sum; rq[grp][sg] = ssq;
    __syncthreads();
    for (int h = 16; h >= 1; h >>= 1) {
        if (grp < h) { rs[grp][sg] += rs[grp + h][sg]; rq[grp][sg] += rq[grp + h][sg]; }
        __syncthreads();
    }
    if (grp == 0) {
        float S1 = rs[0][sg], S2 = rq[0][sg];
        float mean = S1 * (1.0f / 1024.0f);
        float ssc = fmaxf(S2 - 1024.0f * mean * mean, 0.0f);
        stat[0][sg] = mean;
        stat[1][sg] = 1.0f / (sqrtf(ssc) * (1.0f / 32.0f) + 1e-5f);
    }
    __syncthreads();
    float mean = stat[0][sg], inv = stat[1][sg];
    size_t tbase = (((size_t)b << 10) + s) * 1024 + grp * 32;
    #pragma unroll
    for (int j0 = 0; j0 < 32; j0 += 4) {
        unsigned short uh[4], ul[4];
        #pragma unroll
        for (int jj = 0; jj < 4; ++jj) {
            float o = (v[j0 + jj] - mean) * inv;
            o = (o >= 0.f) ? o : 0.02f * o;
            uh[jj] = f2bf(o);
            ul[jj] = f2bf(o - bf2f(uh[jj]));
        }
        *(ushort4*)(oh + tbase + j0) = (ushort4){uh[0], uh[1], uh[2], uh[3]};
        *(ushort4*)(ol + tbase + j0) = (ushort4){ul[0], ul[1], ul[2], ul[3]};
    }
}

// --- normgate: gated combine + norm + leaky + gate2; reads TRANSPOSED h1T[b][s][3072]
__global__ __launch_bounds__(256) void normgate_kernel(
    const float* __restrict__ h1T, const float* __restrict__ wg,
    unsigned short* __restrict__ outT, int* __restrict__ idx, float* __restrict__ acc)
{
    int blk = blockIdx.x;
    int b = blk >> 7;
    int s0 = (blk & 127) * 8;
    int tid = threadIdx.x;
    int sg = tid & 7, grp = tid >> 3;
    int s = s0 + sg;
    const float* row = h1T + ((size_t)((b << 10) + s)) * 3072;
    float v[32];
    float sum = 0.f, ssq = 0.f;
    #pragma unroll
    for (int j0 = 0; j0 < 32; j0 += 4) {
        int i = grp * 32 + j0;
        float4 av = *(const float4*)(row + i);
        float4 mv = *(const float4*)(row + 1024 + i);
        float4 dv = *(const float4*)(row + 2048 + i);
        float x0 = av.x * mv.x + dv.x;
        float x1 = av.y * mv.y + dv.y;
        float x2 = av.z * mv.z + dv.z;
        float x3 = av.w * mv.w + dv.w;
        v[j0] = x0; v[j0 + 1] = x1; v[j0 + 2] = x2; v[j0 + 3] = x3;
        sum += x0 + x1 + x2 + x3;
        ssq += x0 * x0 + x1 * x1 + x2 * x2 + x3 * x3;
    }
    __shared__ float rs[32][8], rq[32][8], stat[2][8];
    rs[grp][sg] = sum; rq[grp][sg] = ssq;
    __syncthreads();
    for (int h = 16; h >= 1; h >>= 1) {
        if (grp < h) { rs[grp][sg] += rs[grp + h][sg]; rq[grp][sg] += rq[grp + h][sg]; }
        __syncthreads();
    }
    if (grp == 0) {
        float S1 = rs[0][sg], S2 = rq[0][sg];
        float mean = S1 * (1.0f / 1024.0f);
        float ssc = fmaxf(S2 - 1024.0f * mean * mean, 0.0f);
        stat[0][sg] = mean;
        stat[1][sg] = 1.0f / (sqrtf(ssc) * (1.0f / 32.0f) + 1e-5f);
    }
    __syncthreads();
    float mean = stat[0][sg], inv = stat[1][sg];
    float l0 = 0.f, l1 = 0.f, l2 = 0.f, l3 = 0.f;
    size_t tbase = (((size_t)b << 10) + s) * 1024 + grp * 32;
    #pragma unroll
    for (int j0 = 0; j0 < 32; j0 += 4) {
        unsigned short u[4];
        #pragma unroll
        for (int jj = 0; jj < 4; ++jj) {
            int i = grp * 32 + j0 + jj;
            float o = (v[j0 + jj] - mean) * inv;
            o = (o >= 0.f) ? o : 0.02f * o;
            u[jj] = f2bf(o);
            l0 += o * wg[i];
            l1 += o * wg[1024 + i];
            l2 += o * wg[2048 + i];
            l3 += o * wg[3072 + i];
        }
        *(ushort4*)(outT + tbase + j0) = (ushort4){u[0], u[1], u[2], u[3]};
    }
    __shared__ float pl[4][32][8];
    __shared__ float la[8];
    pl[0][grp][sg] = l0; pl[1][grp][sg] = l1;
    pl[2][grp][sg] = l2; pl[3][grp][sg] = l3;
    if (tid < 8) la[tid] = 0.f;
    __syncthreads();
    for (int h = 16; h >= 1; h >>= 1) {
        if (grp < h) {
            #pragma unroll
            for (int e = 0; e < 4; ++e) pl[e][grp][sg] += pl[e][grp + h][sg];
        }
        __syncthreads();
    }
    if (grp == 0) {
        float L[4] = {pl[0][0][sg], pl[1][0][sg], pl[2][0][sg], pl[3][0][sg]};
        float m = fmaxf(fmaxf(L[0], L[1]), fmaxf(L[2], L[3]));
        float e0 = expf(L[0] - m), e1 = expf(L[1] - m), e2 = expf(L[2] - m), e3 = expf(L[3] - m);
        float invs = 1.0f / (e0 + e1 + e2 + e3);
        int best = 0; float bv = L[0];
        if (L[1] > bv) { bv = L[1]; best = 1; }
        if (L[2] > bv) { bv = L[2]; best = 2; }
        if (L[3] > bv) { bv = L[3]; best = 3; }
        idx[(b << 10) + s] = best;
        atomicAdd(&la[0], e0 * invs);
        atomicAdd(&la[1], e1 * invs);
        atomicAdd(&la[2], e2 * invs);
        atomicAdd(&la[3], e3 * invs);
        atomicAdd(&la[4 + best], 1.0f);
    }
    __syncthreads();
    if (tid < 8) atomicAdd(&acc[8 + tid], la[tid]);
}

extern "C" void kernel_launch(void* const* d_in, const int* in_sizes, int n_in,
                              void* d_out, int out_size, void* d_ws, size_t ws_size,
                              hipStream_t stream) {
    const float* inp     = (const float*)d_in[0];
    const float* divisor = (const float*)d_in[1];
    const float* w0_gate = (const float*)d_in[2];
    const float* w0      = (const float*)d_in[3];
    const float* w1      = (const float*)d_in[4];
    const float* w2_gate = (const float*)d_in[5];
    const float* w2      = (const float*)d_in[6];
    float* out = (float*)d_out;
    (void)in_sizes; (void)n_in; (void)out_size; (void)ws_size;

    char* ws = (char*)d_ws;
    const unsigned short* base = (const unsigned short*)ws;

    float* h1            = (float*)(ws + 0);                  // 25165824 (also h1T)
    float* g             = (float*)(ws + 25165824);           //  8388608
    unsigned short* gT1h = (unsigned short*)(ws + 33554432);  //  4194304
    unsigned short* gT1l = (unsigned short*)(ws + 37748736);  //  4194304
    unsigned short* w1Th = (unsigned short*)(ws + 41943040);  // 18874368
    unsigned short* w1Tl = (unsigned short*)(ws + 60817408);  // 18874368
    unsigned short* xTh  = (unsigned short*)(ws + 79691776);  //  2097152
    unsigned short* xTl  = (unsigned short*)(ws + 81788928);  //  2097152
    unsigned short* w0Th = (unsigned short*)(ws + 83886080);  // 12582912
    unsigned short* w0Tl = (unsigned short*)(ws + 96468992);  // 12582912
    unsigned short* gT2  = (unsigned short*)(ws + 79691776);  //  4194304 (reuse)
    unsigned short* w2T  = (unsigned short*)(ws + 83886080);  //  4194304 (reuse)
    int* idx1            = (int*)(ws + 109051904);
    int* idx2            = (int*)(ws + 109060096);
    float* acc           = (float*)(ws + 109068288);
    int* perm1           = (int*)(ws + 109076480);
    int* eSort1          = (int*)(ws + 109084672);
    int* perm2           = (int*)(ws + 109092864);
    int* eSort2          = (int*)(ws + 109101056);
    float* zbuf          = (float*)(ws + 109109248);          // 4096 B zeros

    const unsigned int GT1H = 16777216u, GT1L = 18874368u;
    const unsigned int W1TH = 20971520u, W1TL = 30408704u;
    const unsigned int XTH  = 39845888u, XTL  = 40894464u;
    const unsigned int W0TH = 41943040u, W0TL = 48234496u;
    const unsigned int ZB   = 54554624u;                      // zbuf in ushort units

    hipMemsetAsync(acc, 0, 64, stream);
    hipMemsetAsync(zbuf, 0, 4096, stream);

    // fused prep: xT/w0T split transposes + w1 split cvt + gate1
    prep_kernel<<<19712, 256, 0, stream>>>(inp, w0, w1, xTh, xTl, w0Th, w0Tl,
                                           w1Th, w1Tl, w0_gate, idx1, acc);

    sort_kernel<<<2, 1024, 0, stream>>>(idx1, perm1, eSort1);
    // MoE 1 (split), 768-thread 12-wave dbuf
    moe_split_kernel<<<256, 768, 163840, stream>>>(base, XTH, XTL, W0TH, W0TL, perm1, eSort1, h1);

    // cumsum + affine (shfl scan) fused with w2T transpose
    cumsum_w2t_kernel<<<4096, 256, 0, stream>>>(h1, divisor, g, w2, w2T);
    norm0_kernel<<<256, 256, 0, stream>>>(g, gT1h, gT1l);
    // conv (split), 1024-thread 16-wave dbuf, transposed output h1T[b][s][3072]
    conv_split_kernel<<<256, 1024, 141312, stream>>>(base, GT1H, GT1L, W1TH, W1TL, ZB, h1);
    // fused gated-combine + norm + leaky + gate2 (reads h1T)
    normgate_kernel<<<256, 256, 0, stream>>>(h1, w2_gate, gT2, idx2, acc);

    // MoE 2 (plain bf16) + fused loss
    sort_kernel<<<2, 1024, 0, stream>>>(idx2, perm2, eSort2);
    moe_kernel<<<128, 256, 0, stream>>>(gT2, w2T, perm2, eSort2, out, 1024, 512, acc);
}